// Round 1
// baseline (4750.143 us; speedup 1.0000x reference)
//
#include <hip/hip_runtime.h>

// ---------------------------------------------------------------------------
// Fused decoder: B=8192 rows x 40 steps, one WG per 32 rows (grid=256).
// bf16 MFMA (v_mfma_f32_32x32x16_bf16) for all matmuls; weights pre-packed
// into B-fragment order in d_ws by prologue kernels. c-state kept fp32 in
// registers; h/z/y/c_new staged bf16 in LDS. Hawkes intensities precomputed.
// ---------------------------------------------------------------------------

#define BDIM  8192
#define HDIM  256
#define FDIM  128
#define ZDIM  64
#define TDIM  43
#define STEPS 40

typedef __attribute__((ext_vector_type(8)))  __bf16 bf16x8;
typedef __attribute__((ext_vector_type(16))) float  f32x16;

// LDS activation buffer geometry (cols are bf16 elements)
#define ACT_STRIDE 2832   // bytes/row: >= 2*1344+48 stagger, and 708 dwords == 4 (mod 32)
#define C_Z   0           // z_j        (64)
#define C_HI  64          // h_i        (256)
#define C_YP  320         // y_prev     (128)
#define C_H   448         // h          (256)
#define C_C   704         // c_new      (256)
#define C_Y   960         // y (new)    (128)
#define C_T0  1088        // temp: y1 / hz|hzp (128)
#define C_T1  1216        // temp: y2   (128)

// packed-weight offsets in __bf16 elements
#define PW_GATES 0u
#define PW_W1    720896u
#define PW_W2    753664u
#define PW_W3    770048u
#define PW_W4    786432u
#define PW_W5    835584u
#define PW_W6    839680u
#define PW_W7    843776u
#define PW_W8    884736u
#define PW_W9    888832u

__device__ __forceinline__ int act_off(int row, int col) {
  // stagger groups of 8 rows by 16B so the 32-row ds_read_b128 column read
  // spreads across banks (stride 708 dw == 4 mod 32, +4dw per 8-row group)
  return row * ACT_STRIDE + ((row >> 3) << 4) + (col << 1);
}

__device__ __forceinline__ f32x16 mfma32(bf16x8 a, bf16x8 b, f32x16 c) {
  return __builtin_amdgcn_mfma_f32_32x32x16_bf16(a, b, c, 0, 0, 0);
}

__device__ __forceinline__ float sigm(float x) { return 1.f / (1.f + __expf(-x)); }
__device__ __forceinline__ float tanh_f(float x) {
  float t = __expf(-2.f * fabsf(x));
  float r = (1.f - t) / (1.f + t);
  return x < 0.f ? -r : r;
}

__device__ __forceinline__ f32x16 relu_b(f32x16 a, float bv) {
#pragma unroll
  for (int r = 0; r < 16; ++r) a[r] = fmaxf(a[r] + bv, 0.f);
  return a;
}

// one 32-col output tile, M=32 batch rows, accumulate over KT k-tiles of 16
template <int KT, class CF>
__device__ __forceinline__ f32x16 gemmN1(const bf16x8* __restrict__ w, int ntile,
                                         const unsigned char* actb, int rowA, int k8,
                                         int lane, CF colf) {
  f32x16 a0 = {}, a1 = {};
#pragma unroll
  for (int kt = 0; kt < KT; kt += 2) {
    bf16x8 x0 = *(const bf16x8*)(actb + act_off(rowA, colf(kt) + k8));
    bf16x8 w0 = w[((size_t)ntile * KT + kt) * 64 + lane];
    a0 = mfma32(x0, w0, a0);
    bf16x8 x1 = *(const bf16x8*)(actb + act_off(rowA, colf(kt + 1) + k8));
    bf16x8 w1 = w[((size_t)ntile * KT + kt + 1) * 64 + lane];
    a1 = mfma32(x1, w1, a1);
  }
  return a0 + a1;
}

// C-fragment row for 32x32 mfma: row = (reg&3) + 8*(reg>>2) + 4*(lane>>5)
__device__ __forceinline__ int crow(int r, int lane) {
  return (r & 3) + ((r >> 2) << 3) + ((lane >> 5) << 2);
}

__device__ __forceinline__ void store_tile(unsigned char* actb, int col_plus_nl, int lane,
                                           const f32x16& v) {
#pragma unroll
  for (int r = 0; r < 16; ++r) {
    *(__bf16*)(actb + act_off(crow(r, lane), col_plus_nl)) = (__bf16)v[r];
  }
}

// ---------------------------------------------------------------------------
// Prologue: pack W[K][N] (optionally two stacked sources split at splitK) into
// bf16 MFMA B-fragment order: frag f = (ntile*KT + kt)*64 + lane holds
// elements W[kt*16 + (lane>>5)*8 + j][ntile*32 + (lane&31)], j=0..7.
// ---------------------------------------------------------------------------
__global__ __launch_bounds__(256) void pack_w(const float* __restrict__ srcA,
                                              const float* __restrict__ srcB, int splitK,
                                              int K, int N, __bf16* __restrict__ dst) {
  int f = blockIdx.x * 256 + threadIdx.x;
  int KT = K >> 4;
  int total = KT * (N >> 5) * 64;
  if (f >= total) return;
  int lane = f & 63;
  int tile = f >> 6;
  int kt = tile % KT;
  int nt = tile / KT;
  int k0 = kt * 16 + ((lane >> 5) << 3);
  int n = (nt << 5) + (lane & 31);
  bf16x8 v;
#pragma unroll
  for (int j = 0; j < 8; ++j) {
    int k = k0 + j;
    float x = (k < splitK) ? srcA[(size_t)k * N + n] : srcB[(size_t)(k - splitK) * N + n];
    v[j] = (__bf16)x;
  }
  *(bf16x8*)(dst + (size_t)f * 8) = v;
}

struct Params {
  const float *h_i, *input_t, *eps_inf, *eps_prior;
  const float *b_lstm, *b1, *b2, *b3, *b4, *b5, *b6, *b7, *b8, *b9;
  const float *alpha, *beta, *mu0;
  const __bf16* wpack;
  float* out;
};

__global__ __launch_bounds__(256, 1) void decoder_main(Params p) {
  __shared__ __align__(16) unsigned char act[32 * ACT_STRIDE];  // 90624 B
  __shared__ float inten[STEPS * 32];                           // 5120 B
  __shared__ float fbuf[32 * 256];                              // 32768 B

  const int tid = threadIdx.x;
  const int wave = tid >> 6;
  const int lane = tid & 63;
  const int rowA = lane & 31;            // A-fragment row (batch row within tile)
  const int k8 = (lane >> 5) << 3;       // k sub-offset of A/B fragment
  const int nl = lane & 31;              // output column within 32-tile
  const int r0 = blockIdx.x * 32;        // first batch row of this WG

  // zero whole activation buffer, then fill h_i (bf16)
  for (int i = tid; i < (32 * ACT_STRIDE) / 4; i += 256) ((unsigned int*)act)[i] = 0u;
  __syncthreads();
  for (int i = tid; i < 32 * 256; i += 256) {
    int row = i >> 8, col = i & 255;
    *(__bf16*)(act + act_off(row, C_HI + col)) =
        (__bf16)p.h_i[(size_t)(r0 + row) * HDIM + col];
  }
  // Hawkes intensity precompute: depends only on input_t and j
  {
    float ab = p.alpha[0] * p.beta[0], mu = p.mu0[0];
    for (int t = tid; t < 32 * STEPS; t += 256) {
      int row = t & 31, j = t >> 5;
      const float* tp = p.input_t + (size_t)(r0 + row) * TDIM;
      float tc = tp[j + 3];
      float s = 0.f;
      for (int idx = 0; idx < j + 3; ++idx) s += __expf(tp[idx] - tc);
      inten[j * 32 + row] = mu + ab * s;
    }
  }
  f32x16 c_st[2] = {};  // per-wave fp32 cell state, cols wave*64 + p*32 + nl
  __syncthreads();

  const __bf16* W = p.wpack;
  const bf16x8* wg  = (const bf16x8*)(W + PW_GATES);
  const bf16x8* w1p = (const bf16x8*)(W + PW_W1);
  const bf16x8* w2p = (const bf16x8*)(W + PW_W2);
  const bf16x8* w3p = (const bf16x8*)(W + PW_W3);
  const bf16x8* w4p = (const bf16x8*)(W + PW_W4);
  const bf16x8* w5p = (const bf16x8*)(W + PW_W5);
  const bf16x8* w6p = (const bf16x8*)(W + PW_W6);
  const bf16x8* w7p = (const bf16x8*)(W + PW_W7);
  const bf16x8* w8p = (const bf16x8*)(W + PW_W8);
  const bf16x8* w9p = (const bf16x8*)(W + PW_W9);

  float* outy  = p.out;                                   // [B][40][128]
  float* outm  = p.out + (size_t)41943040;                // [B][40][64]
  float* outl  = outm + (size_t)20971520;
  float* outz  = outl + (size_t)20971520;
  float* outzp = outz + (size_t)20971520;

  for (int j = 0; j < STEPS; ++j) {
    // ---- phase 1: gates = [z|h_i|y_prev|h] @ [Wx;Wh], N=1024, K=704 ----
    f32x16 acc[8] = {};
#pragma unroll 2
    for (int kt = 0; kt < 44; ++kt) {
      bf16x8 a = *(const bf16x8*)(act + act_off(rowA, kt * 16 + k8));
#pragma unroll
      for (int t = 0; t < 8; ++t) {
        int ntile = (t >> 1) * 8 + wave * 2 + (t & 1);  // gate g=t>>1, pair p=t&1
        bf16x8 b = wg[((size_t)ntile * 44 + kt) * 64 + lane];
        acc[t] = mfma32(a, b, acc[t]);
      }
    }
    f32x16 cnv[2], hnv[2];
#pragma unroll
    for (int pp = 0; pp < 2; ++pp) {
      int colb = wave * 64 + pp * 32 + nl;
      float bi = p.b_lstm[colb], bff = p.b_lstm[256 + colb];
      float bg = p.b_lstm[512 + colb], bo = p.b_lstm[768 + colb];
#pragma unroll
      for (int r = 0; r < 16; ++r) {
        int row = crow(r, lane);
        float ig = sigm(acc[0 + pp][r] + bi);
        float fg = sigm(acc[2 + pp][r] + bff);
        float gg = tanh_f(acc[4 + pp][r] + bg);
        float og = sigm(acc[6 + pp][r] + bo);
        float cn = fg * c_st[pp][r] + ig * gg;
        float hn = og * tanh_f(cn);
        cnv[pp][r] = cn;
        hnv[pp][r] = hn;
        c_st[pp][r] = inten[j * 32 + row] * cn;  // c_gated carries to next step
      }
    }
    __syncthreads();  // all waves done reading Z/HI/YP/H
#pragma unroll
    for (int pp = 0; pp < 2; ++pp) {
      int colb = wave * 64 + pp * 32 + nl;
#pragma unroll
      for (int r = 0; r < 16; ++r) {
        int row = crow(r, lane);
        *(__bf16*)(act + act_off(row, C_H + colb)) = (__bf16)hnv[pp][r];
        *(__bf16*)(act + act_off(row, C_C + colb)) = (__bf16)cnv[pp][r];
      }
    }
    __syncthreads();

    // ---- phase 2: y1 = relu(h_new @ w1 + b1), N=128 ----
    {
      f32x16 v = gemmN1<16>(w1p, wave, act, rowA, k8, lane,
                            [](int kt) { return C_H + kt * 16; });
      v = relu_b(v, p.b1[wave * 32 + nl]);
      store_tile(act, C_T0 + wave * 32 + nl, lane, v);
    }
    __syncthreads();
    // ---- phase 3: y2 = relu(y1 @ w2 + b2) ----
    {
      f32x16 v = gemmN1<8>(w2p, wave, act, rowA, k8, lane,
                           [](int kt) { return C_T0 + kt * 16; });
      v = relu_b(v, p.b2[wave * 32 + nl]);
      store_tile(act, C_T1 + wave * 32 + nl, lane, v);
    }
    __syncthreads();
    // ---- phase 4: y = relu(y2 @ w3 + b3); write ys + stash in C_Y ----
    {
      f32x16 v = gemmN1<8>(w3p, wave, act, rowA, k8, lane,
                           [](int kt) { return C_T1 + kt * 16; });
      v = relu_b(v, p.b3[wave * 32 + nl]);
      store_tile(act, C_Y + wave * 32 + nl, lane, v);
#pragma unroll
      for (int r = 0; r < 16; ++r) {
        int row = crow(r, lane);
        __builtin_nontemporal_store(
            v[r], outy + (size_t)(r0 + row) * STEPS * FDIM + (size_t)j * FDIM +
                      wave * 32 + nl);
      }
    }
    __syncthreads();

    // ---- phase 5: hz = relu([h_i|c|y|y_prev] @ w4 + b4) (waves 0,1)
    //              hzp = relu([h_i|c|y_prev] @ w7 + b7)   (waves 2,3) ----
    if (wave < 2) {
      auto cf = [](int kt) {
        return kt < 16 ? (C_HI + kt * 16)
                       : kt < 32 ? (C_C + (kt - 16) * 16)
                                 : kt < 40 ? (C_Y + (kt - 32) * 16)
                                           : (C_YP + (kt - 40) * 16);
      };
      f32x16 v = gemmN1<48>(w4p, wave, act, rowA, k8, lane, cf);
      v = relu_b(v, p.b4[wave * 32 + nl]);
      store_tile(act, C_T0 + wave * 32 + nl, lane, v);
    } else {
      auto cf = [](int kt) {
        return kt < 16 ? (C_HI + kt * 16)
                       : kt < 32 ? (C_C + (kt - 16) * 16) : (C_YP + (kt - 32) * 16);
      };
      f32x16 v = gemmN1<40>(w7p, wave - 2, act, rowA, k8, lane, cf);
      v = relu_b(v, p.b7[(wave - 2) * 32 + nl]);
      store_tile(act, C_T0 + 64 + (wave - 2) * 32 + nl, lane, v);
    }
    __syncthreads();

    // ---- phase 6: mean_j/lv_j from hz (waves 0,1), mean_p/lv_p from hzp
    //      (waves 2,3); results to fbuf fp32 ----
    {
      const bf16x8* wsel = (wave == 0) ? w5p : (wave == 1) ? w6p : (wave == 2) ? w8p : w9p;
      const float* bsel = (wave == 0) ? p.b5 : (wave == 1) ? p.b6 : (wave == 2) ? p.b8 : p.b9;
      int colA = (wave < 2) ? C_T0 : (C_T0 + 64);
      auto cf = [colA](int kt) { return colA + kt * 16; };
      f32x16 m0 = gemmN1<4>(wsel, 0, act, rowA, k8, lane, cf);
      f32x16 m1 = gemmN1<4>(wsel, 1, act, rowA, k8, lane, cf);
      m0 = relu_b(m0, bsel[nl]);
      m1 = relu_b(m1, bsel[32 + nl]);
#pragma unroll
      for (int r = 0; r < 16; ++r) {
        int row = crow(r, lane);
        fbuf[row * 256 + wave * 64 + nl] = m0[r];
        fbuf[row * 256 + wave * 64 + 32 + nl] = m1[r];
      }
    }
    __syncthreads();

    // ---- phase 7: z sampling, outputs, z->Z0, y->y_prev ----
#pragma unroll
    for (int kk = 0; kk < 8; ++kk) {
      int e = kk * 256 + tid;
      int row = e >> 6, col = e & 63;
      int b = r0 + row;
      float mean = fbuf[row * 256 + col];
      float lv = fbuf[row * 256 + 64 + col];
      float mp2 = fbuf[row * 256 + 128 + col];
      float lp = fbuf[row * 256 + 192 + col];
      size_t eoff = ((size_t)j * BDIM + b) * ZDIM + col;
      float ei = __builtin_nontemporal_load(p.eps_inf + eoff);
      float ep = __builtin_nontemporal_load(p.eps_prior + eoff);
      float zn = mean + ei * __expf(0.5f * lv);
      float zp = mp2 + ep * __expf(0.5f * lp);
      size_t ob = ((size_t)b * STEPS + j) * ZDIM + col;
      __builtin_nontemporal_store(mean, outm + ob);
      __builtin_nontemporal_store(lv, outl + ob);
      __builtin_nontemporal_store(zn, outz + ob);
      __builtin_nontemporal_store(zp, outzp + ob);
      *(__bf16*)(act + act_off(row, C_Z + col)) = (__bf16)zn;
    }
#pragma unroll
    for (int kk = 0; kk < 16; ++kk) {
      int e = kk * 256 + tid;
      int row = e >> 7, col = e & 127;
      *(__bf16*)(act + act_off(row, C_YP + col)) =
          *(const __bf16*)(act + act_off(row, C_Y + col));
    }
    __syncthreads();
  }
}

extern "C" void kernel_launch(void* const* d_in, const int* in_sizes, int n_in,
                              void* d_out, int out_size, void* d_ws, size_t ws_size,
                              hipStream_t stream) {
  const float* h_i = (const float*)d_in[0];
  const float* input_t = (const float*)d_in[1];
  const float* eps_inf = (const float*)d_in[2];
  const float* eps_prior = (const float*)d_in[3];
  const float* Wx = (const float*)d_in[4];
  const float* Wh = (const float*)d_in[5];
  const float* b_lstm = (const float*)d_in[6];
  const float* w1 = (const float*)d_in[7];  const float* b1 = (const float*)d_in[8];
  const float* w2 = (const float*)d_in[9];  const float* b2 = (const float*)d_in[10];
  const float* w3 = (const float*)d_in[11]; const float* b3 = (const float*)d_in[12];
  const float* w4 = (const float*)d_in[13]; const float* b4 = (const float*)d_in[14];
  const float* w5 = (const float*)d_in[15]; const float* b5 = (const float*)d_in[16];
  const float* w6 = (const float*)d_in[17]; const float* b6 = (const float*)d_in[18];
  const float* w7 = (const float*)d_in[19]; const float* b7 = (const float*)d_in[20];
  const float* w8 = (const float*)d_in[21]; const float* b8 = (const float*)d_in[22];
  const float* w9 = (const float*)d_in[23]; const float* b9 = (const float*)d_in[24];
  const float* alpha = (const float*)d_in[25];
  const float* beta = (const float*)d_in[26];
  const float* mu0 = (const float*)d_in[27];
  __bf16* ws = (__bf16*)d_ws;

  auto L = [&](const float* A, const float* Bx, int splitK, int K, int N, unsigned off) {
    int total = (K / 16) * (N / 32) * 64;
    pack_w<<<(total + 255) / 256, 256, 0, stream>>>(A, Bx, splitK, K, N, ws + off);
  };
  L(Wx, Wh, 448, 704, 1024, PW_GATES);  // [Wx;Wh] stacked -> K=704
  L(w1, w1, 256, 256, 128, PW_W1);
  L(w2, w2, 128, 128, 128, PW_W2);
  L(w3, w3, 128, 128, 128, PW_W3);
  L(w4, w4, 768, 768, 64, PW_W4);
  L(w5, w5, 64, 64, 64, PW_W5);
  L(w6, w6, 64, 64, 64, PW_W6);
  L(w7, w7, 640, 640, 64, PW_W7);
  L(w8, w8, 64, 64, 64, PW_W8);
  L(w9, w9, 64, 64, 64, PW_W9);

  Params p;
  p.h_i = h_i; p.input_t = input_t; p.eps_inf = eps_inf; p.eps_prior = eps_prior;
  p.b_lstm = b_lstm; p.b1 = b1; p.b2 = b2; p.b3 = b3; p.b4 = b4; p.b5 = b5;
  p.b6 = b6; p.b7 = b7; p.b8 = b8; p.b9 = b9;
  p.alpha = alpha; p.beta = beta; p.mu0 = mu0;
  p.wpack = ws;
  p.out = (float*)d_out;

  decoder_main<<<256, 256, 0, stream>>>(p);
}

// Round 2
// 3521.426 us; speedup vs baseline: 1.3489x; 1.3489x over previous
//
#include <hip/hip_runtime.h>

// ---------------------------------------------------------------------------
// Fused decoder: B=8192 rows x 40 steps, one WG per 32 rows (grid=256).
// 512 threads = 8 waves (2/SIMD). bf16 MFMA 32x32x16. h_i-constant GEMM parts
// folded out of the recurrence (gates bias in fp32 regs, inf/prior bias bf16
// in LDS). Prior net runs on waves 4-7 concurrently with y-chain on 0-3.
// ---------------------------------------------------------------------------

#define BDIM  8192
#define HDIM  256
#define FDIM  128
#define ZDIM  64
#define TDIM  43
#define STEPS 40

typedef __attribute__((ext_vector_type(8)))  __bf16 bf16x8;
typedef __attribute__((ext_vector_type(16))) float  f32x16;

// LDS activation buffer (cols are bf16 elements)
#define ACT_STRIDE 3248   // bytes/row: 812 dw == 12 (mod 32) -> all 8 16B slots hit
#define C_Z   0           // z          (64)
#define C_YP  64          // y_prev     (128)
#define C_H0  192         // h buf 0    (256)
#define C_H1  448         // h buf 1    (256)
#define C_C   704         // c_new      (256)
#define C_Y   960         // y          (128)
#define C_T0  1088        // y1         (128)
#define C_T1  1216        // y2         (128)
#define C_HZ  1344        // hz  (inf)  (64)
#define C_HZP 1408        // hzp (prior)(64)
#define C_B4  1472        // h_i@w4+b4 fold, bf16 (64)
#define C_B7  1536        // h_i@w7+b7 fold, bf16 (64)  -> 1600 cols total

// packed-weight offsets in __bf16 elements
#define PW_GS  0u         // gates step part [z|yp|h] K=448 N=1024 (28 kt)
#define PW_GHI 458752u    // gates h_i part K=256 N=1024 (16 kt)
#define PW_W1  720896u
#define PW_W2  753664u
#define PW_W3  770048u
#define PW_W4S 786432u    // w4 rows [256:768) = [c|y|yp], K=512 N=64 (32 kt)
#define PW_W4H 819200u    // w4 rows [0:256)  = h_i part
#define PW_W5  835584u
#define PW_W6  839680u
#define PW_W7S 843776u    // w7 rows [256:640) = [c|yp], K=384 N=64 (24 kt)
#define PW_W7H 868352u
#define PW_W8  884736u
#define PW_W9  888832u

__device__ __forceinline__ int act_off(int row, int col) {
  return row * ACT_STRIDE + ((row >> 3) << 4) + (col << 1);
}

__device__ __forceinline__ f32x16 mfma32(bf16x8 a, bf16x8 b, f32x16 c) {
  return __builtin_amdgcn_mfma_f32_32x32x16_bf16(a, b, c, 0, 0, 0);
}

__device__ __forceinline__ float sigm(float x) { return 1.f / (1.f + __expf(-x)); }
__device__ __forceinline__ float tanh_f(float x) {
  float t = __expf(-2.f * fabsf(x));
  float r = (1.f - t) / (1.f + t);
  return x < 0.f ? -r : r;
}

__device__ __forceinline__ f32x16 relu_b(f32x16 a, float bv) {
#pragma unroll
  for (int r = 0; r < 16; ++r) a[r] = fmaxf(a[r] + bv, 0.f);
  return a;
}

template <int KT, class CF>
__device__ __forceinline__ f32x16 gemmN1(const bf16x8* __restrict__ w, int ntile,
                                         const unsigned char* actb, int rowA, int k8,
                                         int lane, CF colf) {
  f32x16 a0 = {}, a1 = {};
#pragma unroll
  for (int kt = 0; kt < KT; kt += 2) {
    bf16x8 x0 = *(const bf16x8*)(actb + act_off(rowA, colf(kt) + k8));
    bf16x8 w0 = w[((size_t)ntile * KT + kt) * 64 + lane];
    a0 = mfma32(x0, w0, a0);
    bf16x8 x1 = *(const bf16x8*)(actb + act_off(rowA, colf(kt + 1) + k8));
    bf16x8 w1 = w[((size_t)ntile * KT + kt + 1) * 64 + lane];
    a1 = mfma32(x1, w1, a1);
  }
  return a0 + a1;
}

__device__ __forceinline__ int crow(int r, int lane) {
  return (r & 3) + ((r >> 2) << 3) + ((lane >> 5) << 2);
}

__device__ __forceinline__ void store_tile(unsigned char* actb, int col_plus_nl, int lane,
                                           const f32x16& v) {
#pragma unroll
  for (int r = 0; r < 16; ++r) {
    *(__bf16*)(actb + act_off(crow(r, lane), col_plus_nl)) = (__bf16)v[r];
  }
}

// ---------------------------------------------------------------------------
// Prologue: pack (up to 3 row-segments stacked along K) into bf16 B-fragments:
// frag f = (ntile*KT + kt)*64 + lane holds W[kt*16 + (lane>>5)*8 + j][ntile*32
// + (lane&31)], j=0..7. All sources have row length == N.
// ---------------------------------------------------------------------------
struct PSeg { const float* p; int row0; int len; };

__global__ __launch_bounds__(256) void pack_w(PSeg s0, PSeg s1, PSeg s2,
                                              int K, int N, __bf16* __restrict__ dst) {
  int f = blockIdx.x * 256 + threadIdx.x;
  int KT = K >> 4;
  int total = KT * (N >> 5) * 64;
  if (f >= total) return;
  int lane = f & 63;
  int tile = f >> 6;
  int kt = tile % KT;
  int nt = tile / KT;
  int k0 = kt * 16 + ((lane >> 5) << 3);
  int n = (nt << 5) + (lane & 31);
  bf16x8 v;
#pragma unroll
  for (int j = 0; j < 8; ++j) {
    int k = k0 + j;
    const float* src;
    int r;
    if (k < s0.len) { src = s0.p; r = s0.row0 + k; }
    else if (k < s0.len + s1.len) { src = s1.p; r = s1.row0 + (k - s0.len); }
    else { src = s2.p; r = s2.row0 + (k - s0.len - s1.len); }
    v[j] = (__bf16)src[(size_t)r * N + n];
  }
  *(bf16x8*)(dst + (size_t)f * 8) = v;
}

struct Params {
  const float *h_i, *input_t, *eps_inf, *eps_prior;
  const float *b_lstm, *b1, *b2, *b3, *b4, *b5, *b6, *b7, *b8, *b9;
  const float *alpha, *beta, *mu0;
  const __bf16* wpack;
  float* out;
};

__global__ __launch_bounds__(512, 2) void decoder_main(Params p) {
  __shared__ __align__(16) unsigned char act[32 * ACT_STRIDE];  // 103936 B
  __shared__ float inten[STEPS * 32];                           // 5120 B
  __shared__ float fbuf[12288];                                 // 49152 B

  const int tid = threadIdx.x;
  const int wave = tid >> 6;
  const int lane = tid & 63;
  const int rowA = lane & 31;
  const int k8 = (lane >> 5) << 3;
  const int nl = lane & 31;
  const int r0 = blockIdx.x * 32;

  for (int i = tid; i < (32 * ACT_STRIDE) / 4; i += 512) ((unsigned int*)act)[i] = 0u;
  __syncthreads();
  // stage h_i bf16 into C_C (temporary, used only for the fold GEMMs)
  for (int i = tid; i < 32 * 256; i += 512) {
    int row = i >> 8, col = i & 255;
    *(__bf16*)(act + act_off(row, C_C + col)) =
        (__bf16)p.h_i[(size_t)(r0 + row) * HDIM + col];
  }
  {
    float ab = p.alpha[0] * p.beta[0], mu = p.mu0[0];
    for (int t = tid; t < 32 * STEPS; t += 512) {
      int row = t & 31, j = t >> 5;
      const float* tp = p.input_t + (size_t)(r0 + row) * TDIM;
      float tc = tp[j + 3];
      float s = 0.f;
      for (int idx = 0; idx < j + 3; ++idx) s += __expf(tp[idx] - tc);
      inten[j * 32 + row] = mu + ab * s;
    }
  }
  __syncthreads();

  const __bf16* W = p.wpack;
  const bf16x8* wgs = (const bf16x8*)(W + PW_GS);
  const bf16x8* wghi = (const bf16x8*)(W + PW_GHI);
  const bf16x8* w1p = (const bf16x8*)(W + PW_W1);
  const bf16x8* w2p = (const bf16x8*)(W + PW_W2);
  const bf16x8* w3p = (const bf16x8*)(W + PW_W3);
  const bf16x8* w4s = (const bf16x8*)(W + PW_W4S);
  const bf16x8* w4h = (const bf16x8*)(W + PW_W4H);
  const bf16x8* w5p = (const bf16x8*)(W + PW_W5);
  const bf16x8* w6p = (const bf16x8*)(W + PW_W6);
  const bf16x8* w7s = (const bf16x8*)(W + PW_W7S);
  const bf16x8* w7h = (const bf16x8*)(W + PW_W7H);
  const bf16x8* w8p = (const bf16x8*)(W + PW_W8);
  const bf16x8* w9p = (const bf16x8*)(W + PW_W9);

  // ---- one-time folds: gb[g] = h_i@Wx_hi + b_lstm (fp32 regs, per col-tile)
  f32x16 gb[4] = {};
  {
#pragma unroll
    for (int kt = 0; kt < 16; ++kt) {
      bf16x8 a = *(const bf16x8*)(act + act_off(rowA, C_C + kt * 16 + k8));
#pragma unroll
      for (int g = 0; g < 4; ++g)
        gb[g] = mfma32(a, wghi[((size_t)(g * 8 + wave) * 16 + kt) * 64 + lane], gb[g]);
    }
#pragma unroll
    for (int g = 0; g < 4; ++g) {
      float bv = p.b_lstm[g * 256 + wave * 32 + nl];
#pragma unroll
      for (int r = 0; r < 16; ++r) gb[g][r] += bv;
    }
  }
  if (wave < 4) {  // h_i@w4h+b4 -> C_B4 (bf16), h_i@w7h+b7 -> C_B7
    const bf16x8* wp = (wave < 2) ? w4h : w7h;
    int tp2 = wave & 1;
    f32x16 v = gemmN1<16>(wp, tp2, act, rowA, k8, lane,
                          [](int kt) { return C_C + kt * 16; });
    const float* bb = (wave < 2) ? p.b4 : p.b7;
    int cb = (wave < 2) ? C_B4 : C_B7;
    float bv = bb[tp2 * 32 + nl];
#pragma unroll
    for (int r = 0; r < 16; ++r)
      *(__bf16*)(act + act_off(crow(r, lane), cb + tp2 * 32 + nl)) = (__bf16)(v[r] + bv);
  }
  f32x16 c_st = {};
  __syncthreads();

  float* outy = p.out;                                      // [B][40][128]
  float* outm = p.out + (size_t)BDIM * STEPS * FDIM;        // [B][40][64]
  float* outl = outm + (size_t)BDIM * STEPS * ZDIM;
  float* outz = outl + (size_t)BDIM * STEPS * ZDIM;
  float* outzp = outz + (size_t)BDIM * STEPS * ZDIM;

  for (int j = 0; j < STEPS; ++j) {
    const int hR = (j & 1) ? C_H1 : C_H0;
    const int hW = (j & 1) ? C_H0 : C_H1;

    // ---- A: gates = [z|yp|h]@Wgs + gb; wave w owns cols w*32 of all 4 gates
    {
      f32x16 a0 = gb[0], a1 = gb[1], a2 = gb[2], a3 = gb[3];
#pragma unroll
      for (int kt = 0; kt < 28; ++kt) {
        int col = (kt < 12) ? kt * 16 : hR + (kt - 12) * 16;
        bf16x8 a = *(const bf16x8*)(act + act_off(rowA, col + k8));
        a0 = mfma32(a, wgs[((size_t)(0 * 8 + wave) * 28 + kt) * 64 + lane], a0);
        a1 = mfma32(a, wgs[((size_t)(1 * 8 + wave) * 28 + kt) * 64 + lane], a1);
        a2 = mfma32(a, wgs[((size_t)(2 * 8 + wave) * 28 + kt) * 64 + lane], a2);
        a3 = mfma32(a, wgs[((size_t)(3 * 8 + wave) * 28 + kt) * 64 + lane], a3);
      }
#pragma unroll
      for (int r = 0; r < 16; ++r) {
        int row = crow(r, lane);
        float ig = sigm(a0[r]);
        float fg = sigm(a1[r]);
        float gg = tanh_f(a2[r]);
        float og = sigm(a3[r]);
        float cn = fg * c_st[r] + ig * gg;
        float hn = og * tanh_f(cn);
        c_st[r] = inten[j * 32 + row] * cn;  // gated state carries to next step
        *(__bf16*)(act + act_off(row, C_C + wave * 32 + nl)) = (__bf16)cn;
        *(__bf16*)(act + act_off(row, hW + wave * 32 + nl)) = (__bf16)hn;
      }
    }
    __syncthreads();

    // ---- B: w0-3 y1 = relu(h@w1+b1); w4-7 prior partials [c|yp]@w7s
    if (wave < 4) {
      f32x16 v = gemmN1<16>(w1p, wave, act, rowA, k8, lane,
                            [hW](int kt) { return hW + kt * 16; });
      v = relu_b(v, p.b1[wave * 32 + nl]);
      store_tile(act, C_T0 + wave * 32 + nl, lane, v);
    } else {
      int tp2 = wave & 1, kh = (wave >> 1) & 1;
      f32x16 v = {};
#pragma unroll
      for (int kk = 0; kk < 12; ++kk) {
        int kt = kh * 12 + kk;
        int col = (kt < 16) ? (C_C + kt * 16) : (C_YP + (kt - 16) * 16);
        bf16x8 a = *(const bf16x8*)(act + act_off(rowA, col + k8));
        v = mfma32(a, w7s[((size_t)tp2 * 24 + kt) * 64 + lane], v);
      }
#pragma unroll
      for (int r = 0; r < 16; ++r)
        fbuf[kh * 2048 + crow(r, lane) * 64 + tp2 * 32 + nl] = v[r];
    }
    __syncthreads();

    // ---- C: w0-3 y2; w4-7 reduce prior partials + bias fold -> hzp
    if (wave < 4) {
      f32x16 v = gemmN1<8>(w2p, wave, act, rowA, k8, lane,
                           [](int kt) { return C_T0 + kt * 16; });
      v = relu_b(v, p.b2[wave * 32 + nl]);
      store_tile(act, C_T1 + wave * 32 + nl, lane, v);
    } else {
      int t2 = tid & 255;
#pragma unroll
      for (int i = 0; i < 8; ++i) {
        int e = t2 + i * 256;
        int row = e >> 6, col = e & 63;
        float s = fbuf[e] + fbuf[2048 + e] +
                  (float)*(const __bf16*)(act + act_off(row, C_B7 + col));
        s = fmaxf(s, 0.f);
        *(__bf16*)(act + act_off(row, C_HZP + col)) = (__bf16)s;
      }
    }
    __syncthreads();

    // ---- D: w0-3 y = relu(y2@w3+b3) -> C_Y + global; w4-7 mean_p/lv_p
    if (wave < 4) {
      f32x16 v = gemmN1<8>(w3p, wave, act, rowA, k8, lane,
                           [](int kt) { return C_T1 + kt * 16; });
      v = relu_b(v, p.b3[wave * 32 + nl]);
      store_tile(act, C_Y + wave * 32 + nl, lane, v);
#pragma unroll
      for (int r = 0; r < 16; ++r)
        __builtin_nontemporal_store(
            v[r], outy + ((size_t)(r0 + crow(r, lane)) * STEPS + j) * FDIM +
                      wave * 32 + nl);
    } else {
      int sel = (wave - 4) >> 1;  // 0: mean_p (w8), 1: lv_p (w9)
      int tp2 = wave & 1;
      const bf16x8* wp = sel ? w9p : w8p;
      const float* bb = sel ? p.b9 : p.b8;
      f32x16 v = gemmN1<4>(wp, tp2, act, rowA, k8, lane,
                           [](int kt) { return C_HZP + kt * 16; });
      v = relu_b(v, bb[tp2 * 32 + nl]);
#pragma unroll
      for (int r = 0; r < 16; ++r)
        fbuf[8192 + sel * 2048 + crow(r, lane) * 64 + tp2 * 32 + nl] = v[r];
    }
    __syncthreads();

    // ---- E: inf hz partials: [c|y|yp]@w4s, 2 tiles x 4 k-quarters, 8 waves
    {
      int te = wave & 1, kq = wave >> 1;
      f32x16 v = {};
#pragma unroll
      for (int kk = 0; kk < 8; ++kk) {
        int kt = kq * 8 + kk;
        int col = (kt < 24) ? (C_C + kt * 16) : (C_YP + (kt - 24) * 16);
        bf16x8 a = *(const bf16x8*)(act + act_off(rowA, col + k8));
        v = mfma32(a, w4s[((size_t)te * 32 + kt) * 64 + lane], v);
      }
#pragma unroll
      for (int r = 0; r < 16; ++r)
        fbuf[kq * 2048 + crow(r, lane) * 64 + te * 32 + nl] = v[r];
    }
    __syncthreads();

    // ---- F1: reduce hz partials + bias fold -> C_HZ (all 512 threads)
#pragma unroll
    for (int i = 0; i < 4; ++i) {
      int e = tid + i * 512;
      int row = e >> 6, col = e & 63;
      float s = fbuf[e] + fbuf[2048 + e] + fbuf[4096 + e] + fbuf[6144 + e] +
                (float)*(const __bf16*)(act + act_off(row, C_B4 + col));
      s = fmaxf(s, 0.f);
      *(__bf16*)(act + act_off(row, C_HZ + col)) = (__bf16)s;
    }
    __syncthreads();

    // ---- F2: w0-3 mean_j/lv_j from hz; w4-7 sample z_p + store
    if (wave < 4) {
      int sel = wave >> 1;  // 0: mean (w5), 1: lv (w6)
      int tp2 = wave & 1;
      const bf16x8* wp = sel ? w6p : w5p;
      const float* bb = sel ? p.b6 : p.b5;
      f32x16 v = gemmN1<4>(wp, tp2, act, rowA, k8, lane,
                           [](int kt) { return C_HZ + kt * 16; });
      v = relu_b(v, bb[tp2 * 32 + nl]);
#pragma unroll
      for (int r = 0; r < 16; ++r)
        fbuf[sel * 2048 + crow(r, lane) * 64 + tp2 * 32 + nl] = v[r];
    } else {
      int t2 = tid & 255;
#pragma unroll
      for (int i = 0; i < 8; ++i) {
        int e = t2 + i * 256;
        int row = e >> 6, col = e & 63;
        float mp2 = fbuf[8192 + e];
        float lp = fbuf[10240 + e];
        float ep = __builtin_nontemporal_load(
            p.eps_prior + ((size_t)j * BDIM + r0 + row) * ZDIM + col);
        float zp = mp2 + ep * __expf(0.5f * lp);
        __builtin_nontemporal_store(
            zp, outzp + ((size_t)(r0 + row) * STEPS + j) * ZDIM + col);
      }
    }
    __syncthreads();

    // ---- G: sample z_inf, store outputs, z -> C_Z, y -> C_YP
#pragma unroll
    for (int i = 0; i < 4; ++i) {
      int e = tid + i * 512;
      int row = e >> 6, col = e & 63;
      float mean = fbuf[e], lv = fbuf[2048 + e];
      float ei = __builtin_nontemporal_load(
          p.eps_inf + ((size_t)j * BDIM + r0 + row) * ZDIM + col);
      float zn = mean + ei * __expf(0.5f * lv);
      size_t ob = ((size_t)(r0 + row) * STEPS + j) * ZDIM + col;
      __builtin_nontemporal_store(mean, outm + ob);
      __builtin_nontemporal_store(lv, outl + ob);
      __builtin_nontemporal_store(zn, outz + ob);
      *(__bf16*)(act + act_off(row, C_Z + col)) = (__bf16)zn;
    }
#pragma unroll
    for (int i = 0; i < 8; ++i) {
      int e = tid + i * 512;
      int row = e >> 7, col = e & 127;
      *(__bf16*)(act + act_off(row, C_YP + col)) =
          *(const __bf16*)(act + act_off(row, C_Y + col));
    }
    __syncthreads();
  }
}

extern "C" void kernel_launch(void* const* d_in, const int* in_sizes, int n_in,
                              void* d_out, int out_size, void* d_ws, size_t ws_size,
                              hipStream_t stream) {
  const float* h_i = (const float*)d_in[0];
  const float* input_t = (const float*)d_in[1];
  const float* eps_inf = (const float*)d_in[2];
  const float* eps_prior = (const float*)d_in[3];
  const float* Wx = (const float*)d_in[4];
  const float* Wh = (const float*)d_in[5];
  const float* b_lstm = (const float*)d_in[6];
  const float* w1 = (const float*)d_in[7];  const float* b1 = (const float*)d_in[8];
  const float* w2 = (const float*)d_in[9];  const float* b2 = (const float*)d_in[10];
  const float* w3 = (const float*)d_in[11]; const float* b3 = (const float*)d_in[12];
  const float* w4 = (const float*)d_in[13]; const float* b4 = (const float*)d_in[14];
  const float* w5 = (const float*)d_in[15]; const float* b5 = (const float*)d_in[16];
  const float* w6 = (const float*)d_in[17]; const float* b6 = (const float*)d_in[18];
  const float* w7 = (const float*)d_in[19]; const float* b7 = (const float*)d_in[20];
  const float* w8 = (const float*)d_in[21]; const float* b8 = (const float*)d_in[22];
  const float* w9 = (const float*)d_in[23]; const float* b9 = (const float*)d_in[24];
  const float* alpha = (const float*)d_in[25];
  const float* beta = (const float*)d_in[26];
  const float* mu0 = (const float*)d_in[27];
  __bf16* ws = (__bf16*)d_ws;

  auto S = [](const float* ptr, int row0, int len) {
    PSeg s; s.p = ptr; s.row0 = row0; s.len = len; return s;
  };
  PSeg Zs; Zs.p = nullptr; Zs.row0 = 0; Zs.len = 0;
  auto L = [&](PSeg a, PSeg b, PSeg c, int K, int N, unsigned off) {
    int total = (K / 16) * (N / 32) * 64;
    pack_w<<<(total + 255) / 256, 256, 0, stream>>>(a, b, c, K, N, ws + off);
  };
  L(S(Wx, 0, 64), S(Wx, 320, 128), S(Wh, 0, 256), 448, 1024, PW_GS);  // [z|yp|h]
  L(S(Wx, 64, 256), Zs, Zs, 256, 1024, PW_GHI);                        // h_i part
  L(S(w1, 0, 256), Zs, Zs, 256, 128, PW_W1);
  L(S(w2, 0, 128), Zs, Zs, 128, 128, PW_W2);
  L(S(w3, 0, 128), Zs, Zs, 128, 128, PW_W3);
  L(S(w4, 256, 512), Zs, Zs, 512, 64, PW_W4S);  // [c|y|yp]
  L(S(w4, 0, 256), Zs, Zs, 256, 64, PW_W4H);    // h_i part
  L(S(w5, 0, 64), Zs, Zs, 64, 64, PW_W5);
  L(S(w6, 0, 64), Zs, Zs, 64, 64, PW_W6);
  L(S(w7, 256, 384), Zs, Zs, 384, 64, PW_W7S);  // [c|yp]
  L(S(w7, 0, 256), Zs, Zs, 256, 64, PW_W7H);    // h_i part
  L(S(w8, 0, 64), Zs, Zs, 64, 64, PW_W8);
  L(S(w9, 0, 64), Zs, Zs, 64, 64, PW_W9);

  Params p;
  p.h_i = h_i; p.input_t = input_t; p.eps_inf = eps_inf; p.eps_prior = eps_prior;
  p.b_lstm = b_lstm; p.b1 = b1; p.b2 = b2; p.b3 = b3; p.b4 = b4; p.b5 = b5;
  p.b6 = b6; p.b7 = b7; p.b8 = b8; p.b9 = b9;
  p.alpha = alpha; p.beta = beta; p.mu0 = mu0;
  p.wpack = ws;
  p.out = (float*)d_out;

  decoder_main<<<256, 512, 0, stream>>>(p);
}

// Round 3
// 2687.306 us; speedup vs baseline: 1.7676x; 1.3104x over previous
//
#include <hip/hip_runtime.h>

// ---------------------------------------------------------------------------
// Fused decoder: B=8192 x 40 steps, one WG of 1024 threads (16 waves) per 32
// rows, grid=256 (1 WG/CU, 4 waves/SIMD). 16x16x32 bf16 MFMA. Register-lean:
// acc 32 VGPR, h_i-fold gate bias packed bf16 (16 VGPR), c-state fp32 (8).
// Weights pre-packed to B-fragment order. 6 barriers/step.
// ---------------------------------------------------------------------------

#define BDIM  8192
#define HDIM  256
#define FDIM  128
#define ZDIM  64
#define TDIM  43
#define STEPS 40

typedef __attribute__((ext_vector_type(8))) __bf16 bf16x8;
typedef __attribute__((ext_vector_type(4))) float  f32x4;

// LDS activation buffer (cols are bf16 elements)
#define ACT_STRIDE 3248   // bytes/row; 812 dw == 12 (mod 32), +16B stagger per 8 rows
#define C_Z   0           // z          (64)
#define C_Y0  64          // y parity 0 (128)
#define C_Y1  192         // y parity 1 (128)
#define C_H0  320         // h parity 0 (256)
#define C_H1  576         // h parity 1 (256)
#define C_C   832         // c_new      (256)   (holds h_i during startup folds)
#define C_T0  1088        // y1         (128)
#define C_T1  1216        // y2         (128)
#define C_HZ  1344        // hz  (inf)  (64)
#define C_HZP 1408        // hzp (prior)(64)
#define C_B4  1472        // h_i@w4+b4 fold, bf16 (64)
#define C_B7  1536        // h_i@w7+b7 fold, bf16 (64)  -> 1600 cols

// packed-weight offsets in __bf16 elements
#define PW_GS  0u         // gates [z|yp|h] K=448 N=1024 (KT=14)
#define PW_GHI 458752u    // gates h_i part K=256 N=1024 (KT=8)
#define PW_W1  720896u    // K=256 N=128 (KT=8)
#define PW_W2  753664u    // K=128 N=128 (KT=4)
#define PW_W3  770048u    // K=128 N=128 (KT=4)
#define PW_W4S 786432u    // w4 rows 256:768 [c|y|yp] K=512 N=64 (KT=16)
#define PW_W4H 819200u    // w4 rows 0:256 K=256 N=64 (KT=8)
#define PW_W5  835584u    // K=64 N=64 (KT=2)
#define PW_W6  839680u
#define PW_W7S 843776u    // w7 rows 256:640 [c|yp] K=384 N=64 (KT=12)
#define PW_W7H 868352u    // w7 rows 0:256 K=256 N=64 (KT=8)
#define PW_W8  884736u
#define PW_W9  888832u

__device__ __forceinline__ int act_off(int row, int col) {
  return row * ACT_STRIDE + ((row >> 3) << 4) + (col << 1);
}
__device__ __forceinline__ f32x4 mfma16(bf16x8 a, bf16x8 b, f32x4 c) {
  return __builtin_amdgcn_mfma_f32_16x16x32_bf16(a, b, c, 0, 0, 0);
}
__device__ __forceinline__ float sigm(float x) { return 1.f / (1.f + __expf(-x)); }
__device__ __forceinline__ float tanh_f(float x) {
  float t = __expf(-2.f * fabsf(x));
  float r = (1.f - t) / (1.f + t);
  return x < 0.f ? -r : r;
}
// A-fragment read: lane l holds A[mt*16 + (l&15)][k = (l>>4)*8 + j]
__device__ __forceinline__ bf16x8 aread(const unsigned char* actb, int mt, int col,
                                        int lane) {
  return *(const bf16x8*)(actb + act_off(mt * 16 + (lane & 15), col + ((lane >> 4) << 3)));
}
// C-fragment store with bias+relu: row = mt*16 + (lane>>4)*4 + r
__device__ __forceinline__ void st16(unsigned char* actb, int col, int mt, int rsub,
                                     f32x4 v, float bv) {
#pragma unroll
  for (int r = 0; r < 4; ++r)
    *(__bf16*)(actb + act_off(mt * 16 + rsub + r, col)) = (__bf16)fmaxf(v[r] + bv, 0.f);
}
__device__ __forceinline__ unsigned int pk2(float a, float b) {
  union { __bf16 h; unsigned short u; } x, y;
  x.h = (__bf16)a; y.h = (__bf16)b;
  return (unsigned int)x.u | ((unsigned int)y.u << 16);
}
__device__ __forceinline__ float upkf(unsigned int u, int hi) {
  union { unsigned int i; float f; } c;
  c.i = hi ? (u & 0xffff0000u) : (u << 16);
  return c.f;
}

// ---------------------------------------------------------------------------
// Pack (up to 3 K-stacked row segments) into 16-wide B-fragments:
// frag f=(nt*KT+kt)*64+lane holds W[kt*32+(lane>>4)*8+j][nt*16+(lane&15)].
// ---------------------------------------------------------------------------
struct PSeg { const float* p; int row0; int len; };

__global__ __launch_bounds__(256) void pack_w(PSeg s0, PSeg s1, PSeg s2,
                                              int K, int N, __bf16* __restrict__ dst) {
  int f = blockIdx.x * 256 + threadIdx.x;
  int KT = K >> 5;
  int total = KT * (N >> 4) * 64;
  if (f >= total) return;
  int lane = f & 63;
  int tile = f >> 6;
  int kt = tile % KT;
  int nt = tile / KT;
  int k0 = kt * 32 + ((lane >> 4) << 3);
  int n = (nt << 4) + (lane & 15);
  bf16x8 v;
#pragma unroll
  for (int j = 0; j < 8; ++j) {
    int k = k0 + j;
    const float* src;
    int r;
    if (k < s0.len) { src = s0.p; r = s0.row0 + k; }
    else if (k < s0.len + s1.len) { src = s1.p; r = s1.row0 + (k - s0.len); }
    else { src = s2.p; r = s2.row0 + (k - s0.len - s1.len); }
    v[j] = (__bf16)src[(size_t)r * N + n];
  }
  *(bf16x8*)(dst + (size_t)f * 8) = v;
}

struct Params {
  const float *h_i, *input_t, *eps_inf, *eps_prior;
  const float *b_lstm, *b1, *b2, *b3, *b4, *b5, *b6, *b7, *b8, *b9;
  const float *alpha, *beta, *mu0;
  const __bf16* wpack;
  float* out;
};

__global__ __launch_bounds__(1024, 4) void decoder_main(Params p) {
  __shared__ __align__(16) unsigned char act[32 * ACT_STRIDE];  // 103936 B
  __shared__ float fbuf[2048];                                  // 8192 B
  __shared__ float inten[STEPS * 32];                           // 5120 B

  const int tid = threadIdx.x;
  const int w = tid >> 6;
  const int lane = tid & 63;
  const int ln16 = lane & 15;
  const int rsub = (lane >> 4) << 2;
  const int r0 = blockIdx.x * 32;

  for (int i = tid; i < (32 * ACT_STRIDE) / 4; i += 1024) ((unsigned int*)act)[i] = 0u;
  __syncthreads();
  // stage h_i bf16 into C_C (consumed by the startup folds only)
  for (int i = tid; i < 32 * 256; i += 1024) {
    int row = i >> 8, col = i & 255;
    *(__bf16*)(act + act_off(row, C_C + col)) =
        (__bf16)p.h_i[(size_t)(r0 + row) * HDIM + col];
  }
  {
    float ab = p.alpha[0] * p.beta[0], mu = p.mu0[0];
    for (int t = tid; t < 32 * STEPS; t += 1024) {
      int row = t & 31, j = t >> 5;
      const float* tp = p.input_t + (size_t)(r0 + row) * TDIM;
      float tc = tp[j + 3];
      float s = 0.f;
      for (int idx = 0; idx < j + 3; ++idx) s += __expf(tp[idx] - tc);
      inten[j * 32 + row] = mu + ab * s;
    }
  }
  __syncthreads();

  const __bf16* W = p.wpack;
  const bf16x8* wgs = (const bf16x8*)(W + PW_GS);
  const bf16x8* wghi = (const bf16x8*)(W + PW_GHI);
  const bf16x8* w1p = (const bf16x8*)(W + PW_W1);
  const bf16x8* w2p = (const bf16x8*)(W + PW_W2);
  const bf16x8* w3p = (const bf16x8*)(W + PW_W3);
  const bf16x8* w4s = (const bf16x8*)(W + PW_W4S);
  const bf16x8* w4h = (const bf16x8*)(W + PW_W4H);
  const bf16x8* w5p = (const bf16x8*)(W + PW_W5);
  const bf16x8* w6p = (const bf16x8*)(W + PW_W6);
  const bf16x8* w7s = (const bf16x8*)(W + PW_W7S);
  const bf16x8* w7h = (const bf16x8*)(W + PW_W7H);
  const bf16x8* w8p = (const bf16x8*)(W + PW_W8);
  const bf16x8* w9p = (const bf16x8*)(W + PW_W9);

  // ---- startup folds ----
  uint2 gbp[4][2];  // h_i@Wx_hi + b_lstm, packed bf16 per gate/mtile
  {
    f32x4 g[4][2] = {};
#pragma unroll
    for (int kt = 0; kt < 8; ++kt) {
      bf16x8 a0 = aread(act, 0, C_C + kt * 32, lane);
      bf16x8 a1 = aread(act, 1, C_C + kt * 32, lane);
#pragma unroll
      for (int gg = 0; gg < 4; ++gg) {
        bf16x8 b = wghi[((size_t)(gg * 16 + w) * 8 + kt) * 64 + lane];
        g[gg][0] = mfma16(a0, b, g[gg][0]);
        g[gg][1] = mfma16(a1, b, g[gg][1]);
      }
    }
#pragma unroll
    for (int gg = 0; gg < 4; ++gg) {
      float bv = p.b_lstm[gg * 256 + w * 16 + ln16];
#pragma unroll
      for (int mt = 0; mt < 2; ++mt) {
        gbp[gg][mt].x = pk2(g[gg][mt][0] + bv, g[gg][mt][1] + bv);
        gbp[gg][mt].y = pk2(g[gg][mt][2] + bv, g[gg][mt][3] + bv);
      }
    }
  }
  {  // h_i@w4h+b4 -> C_B4 (waves 0-7); h_i@w7h+b7 -> C_B7 (waves 8-15)
    int n = w & 3, mt = (w >> 2) & 1;
    const bf16x8* wp = (w < 8) ? w4h : w7h;
    const float* bb = (w < 8) ? p.b4 : p.b7;
    int cb = (w < 8) ? C_B4 : C_B7;
    f32x4 v = {};
#pragma unroll
    for (int kt = 0; kt < 8; ++kt)
      v = mfma16(aread(act, mt, C_C + kt * 32, lane),
                 wp[(size_t)(n * 8 + kt) * 64 + lane], v);
    float bv = bb[n * 16 + ln16];
#pragma unroll
    for (int r = 0; r < 4; ++r)
      *(__bf16*)(act + act_off(mt * 16 + rsub + r, cb + n * 16 + ln16)) =
          (__bf16)(v[r] + bv);
  }
  f32x4 c_st[2] = {};
  __syncthreads();

  float* outy = p.out;
  float* outm = p.out + (size_t)BDIM * STEPS * FDIM;
  float* outl = outm + (size_t)BDIM * STEPS * ZDIM;
  float* outz = outl + (size_t)BDIM * STEPS * ZDIM;
  float* outzp = outz + (size_t)BDIM * STEPS * ZDIM;

  for (int j = 0; j < STEPS; ++j) {
    const int yW = (j & 1) ? C_Y1 : C_Y0, yR = (j & 1) ? C_Y0 : C_Y1;
    const int hW = (j & 1) ? C_H1 : C_H0, hR = (j & 1) ? C_H0 : C_H1;

    // ---- A: gates = [z|yp|h]@Wgs + gb; wave w owns cols w*16 of all 4 gates
    {
      f32x4 acc[4][2] = {};
#pragma unroll
      for (int kt = 0; kt < 14; ++kt) {
        int col = (kt < 2) ? (C_Z + kt * 32)
                           : (kt < 6) ? (yR + (kt - 2) * 32) : (hR + (kt - 6) * 32);
        bf16x8 a0 = aread(act, 0, col, lane);
        bf16x8 a1 = aread(act, 1, col, lane);
#pragma unroll
        for (int g = 0; g < 4; ++g) {
          bf16x8 b = wgs[((size_t)(g * 16 + w) * 14 + kt) * 64 + lane];
          acc[g][0] = mfma16(a0, b, acc[g][0]);
          acc[g][1] = mfma16(a1, b, acc[g][1]);
        }
      }
#pragma unroll
      for (int mt = 0; mt < 2; ++mt) {
#pragma unroll
        for (int r = 0; r < 4; ++r) {
          int row = mt * 16 + rsub + r;
          unsigned int ui = (r < 2) ? gbp[0][mt].x : gbp[0][mt].y;
          unsigned int uf = (r < 2) ? gbp[1][mt].x : gbp[1][mt].y;
          unsigned int ug = (r < 2) ? gbp[2][mt].x : gbp[2][mt].y;
          unsigned int uo = (r < 2) ? gbp[3][mt].x : gbp[3][mt].y;
          float ig = sigm(acc[0][mt][r] + upkf(ui, r & 1));
          float fg = sigm(acc[1][mt][r] + upkf(uf, r & 1));
          float gg = tanh_f(acc[2][mt][r] + upkf(ug, r & 1));
          float og = sigm(acc[3][mt][r] + upkf(uo, r & 1));
          float cn = fg * c_st[mt][r] + ig * gg;
          float hn = og * tanh_f(cn);
          c_st[mt][r] = inten[j * 32 + row] * cn;
          *(__bf16*)(act + act_off(row, C_C + w * 16 + ln16)) = (__bf16)cn;
          *(__bf16*)(act + act_off(row, hW + w * 16 + ln16)) = (__bf16)hn;
        }
      }
    }
    __syncthreads();

    // ---- B: w0-7 y1 = relu(h@w1+b1); w8-15 full-K prior -> hzp
    if (w < 8) {
      f32x4 a0 = {}, a1 = {};
#pragma unroll
      for (int kt = 0; kt < 8; ++kt) {
        bf16x8 b = w1p[(size_t)(w * 8 + kt) * 64 + lane];
        a0 = mfma16(aread(act, 0, hW + kt * 32, lane), b, a0);
        a1 = mfma16(aread(act, 1, hW + kt * 32, lane), b, a1);
      }
      float bv = p.b1[w * 16 + ln16];
      st16(act, C_T0 + w * 16 + ln16, 0, rsub, a0, bv);
      st16(act, C_T0 + w * 16 + ln16, 1, rsub, a1, bv);
    } else {
      int n = w & 3, mt = (w >> 2) & 1;
      f32x4 v = {};
#pragma unroll
      for (int kt = 0; kt < 12; ++kt) {
        int col = (kt < 8) ? (C_C + kt * 32) : (yR + (kt - 8) * 32);
        v = mfma16(aread(act, mt, col, lane), w7s[(size_t)(n * 12 + kt) * 64 + lane], v);
      }
#pragma unroll
      for (int r = 0; r < 4; ++r) {
        int row = mt * 16 + rsub + r;
        float s = v[r] + (float)*(const __bf16*)(act + act_off(row, C_B7 + n * 16 + ln16));
        *(__bf16*)(act + act_off(row, C_HZP + n * 16 + ln16)) = (__bf16)fmaxf(s, 0.f);
      }
    }
    __syncthreads();

    // ---- C: w0-7 y2; w8-15 mean_p/lv_p + sample zp (prior done)
    if (w < 8) {
      f32x4 a0 = {}, a1 = {};
#pragma unroll
      for (int kt = 0; kt < 4; ++kt) {
        bf16x8 b = w2p[(size_t)(w * 4 + kt) * 64 + lane];
        a0 = mfma16(aread(act, 0, C_T0 + kt * 32, lane), b, a0);
        a1 = mfma16(aread(act, 1, C_T0 + kt * 32, lane), b, a1);
      }
      float bv = p.b2[w * 16 + ln16];
      st16(act, C_T1 + w * 16 + ln16, 0, rsub, a0, bv);
      st16(act, C_T1 + w * 16 + ln16, 1, rsub, a1, bv);
    } else {
      int n = w & 3, mt = (w >> 2) & 1;
      f32x4 vm = {}, vl = {};
#pragma unroll
      for (int kt = 0; kt < 2; ++kt) {
        bf16x8 a = aread(act, mt, C_HZP + kt * 32, lane);
        vm = mfma16(a, w8p[(size_t)(n * 2 + kt) * 64 + lane], vm);
        vl = mfma16(a, w9p[(size_t)(n * 2 + kt) * 64 + lane], vl);
      }
      float bm = p.b8[n * 16 + ln16], bl = p.b9[n * 16 + ln16];
#pragma unroll
      for (int r = 0; r < 4; ++r) {
        int row = mt * 16 + rsub + r, col = n * 16 + ln16;
        float mp = fmaxf(vm[r] + bm, 0.f), lp = fmaxf(vl[r] + bl, 0.f);
        float ep = __builtin_nontemporal_load(
            p.eps_prior + ((size_t)j * BDIM + r0 + row) * ZDIM + col);
        float zp = mp + ep * __expf(0.5f * lp);
        __builtin_nontemporal_store(
            zp, outzp + ((size_t)(r0 + row) * STEPS + j) * ZDIM + col);
      }
    }
    __syncthreads();

    // ---- D: w0-7 y3 -> yW + outy; w8-15 hz partial over [c|yp]
    if (w < 8) {
      f32x4 a0 = {}, a1 = {};
#pragma unroll
      for (int kt = 0; kt < 4; ++kt) {
        bf16x8 b = w3p[(size_t)(w * 4 + kt) * 64 + lane];
        a0 = mfma16(aread(act, 0, C_T1 + kt * 32, lane), b, a0);
        a1 = mfma16(aread(act, 1, C_T1 + kt * 32, lane), b, a1);
      }
      float bv = p.b3[w * 16 + ln16];
#pragma unroll
      for (int mt = 0; mt < 2; ++mt) {
        f32x4 vv = mt ? a1 : a0;
#pragma unroll
        for (int r = 0; r < 4; ++r) {
          int row = mt * 16 + rsub + r;
          float yv = fmaxf(vv[r] + bv, 0.f);
          *(__bf16*)(act + act_off(row, yW + w * 16 + ln16)) = (__bf16)yv;
          __builtin_nontemporal_store(
              yv, outy + ((size_t)(r0 + row) * STEPS + j) * FDIM + w * 16 + ln16);
        }
      }
    } else {
      int a = w - 8, n = a & 3, mt = a >> 2;
      f32x4 v = {};
#pragma unroll
      for (int kt = 0; kt < 8; ++kt)
        v = mfma16(aread(act, mt, C_C + kt * 32, lane),
                   w4s[(size_t)(n * 16 + kt) * 64 + lane], v);
#pragma unroll
      for (int kt = 12; kt < 16; ++kt)
        v = mfma16(aread(act, mt, yR + (kt - 12) * 32, lane),
                   w4s[(size_t)(n * 16 + kt) * 64 + lane], v);
#pragma unroll
      for (int r = 0; r < 4; ++r)
        fbuf[(mt * 16 + rsub + r) * 64 + n * 16 + ln16] = v[r];
    }
    __syncthreads();

    // ---- E: w0-7 hz y-part + combine partial + fold -> C_HZ
    if (w < 8) {
      int n = w & 3, mt = w >> 2;
      f32x4 v = {};
#pragma unroll
      for (int kt = 8; kt < 12; ++kt)
        v = mfma16(aread(act, mt, yW + (kt - 8) * 32, lane),
                   w4s[(size_t)(n * 16 + kt) * 64 + lane], v);
#pragma unroll
      for (int r = 0; r < 4; ++r) {
        int row = mt * 16 + rsub + r, cc = n * 16 + ln16;
        float s = v[r] + fbuf[row * 64 + cc] +
                  (float)*(const __bf16*)(act + act_off(row, C_B4 + cc));
        *(__bf16*)(act + act_off(row, C_HZ + cc)) = (__bf16)fmaxf(s, 0.f);
      }
    }
    __syncthreads();

    // ---- F: w0-7 mean_j/lv_j + sample z -> outputs + C_Z
    if (w < 8) {
      int n = w & 3, mt = w >> 2;
      f32x4 vm = {}, vl = {};
#pragma unroll
      for (int kt = 0; kt < 2; ++kt) {
        bf16x8 a = aread(act, mt, C_HZ + kt * 32, lane);
        vm = mfma16(a, w5p[(size_t)(n * 2 + kt) * 64 + lane], vm);
        vl = mfma16(a, w6p[(size_t)(n * 2 + kt) * 64 + lane], vl);
      }
      float bm = p.b5[n * 16 + ln16], bl = p.b6[n * 16 + ln16];
#pragma unroll
      for (int r = 0; r < 4; ++r) {
        int row = mt * 16 + rsub + r, col = n * 16 + ln16;
        float m = fmaxf(vm[r] + bm, 0.f), l = fmaxf(vl[r] + bl, 0.f);
        float ei = __builtin_nontemporal_load(
            p.eps_inf + ((size_t)j * BDIM + r0 + row) * ZDIM + col);
        float zn = m + ei * __expf(0.5f * l);
        size_t ob = ((size_t)(r0 + row) * STEPS + j) * ZDIM + col;
        __builtin_nontemporal_store(m, outm + ob);
        __builtin_nontemporal_store(l, outl + ob);
        __builtin_nontemporal_store(zn, outz + ob);
        *(__bf16*)(act + act_off(row, C_Z + col)) = (__bf16)zn;
      }
    }
    __syncthreads();
  }
}

extern "C" void kernel_launch(void* const* d_in, const int* in_sizes, int n_in,
                              void* d_out, int out_size, void* d_ws, size_t ws_size,
                              hipStream_t stream) {
  const float* h_i = (const float*)d_in[0];
  const float* input_t = (const float*)d_in[1];
  const float* eps_inf = (const float*)d_in[2];
  const float* eps_prior = (const float*)d_in[3];
  const float* Wx = (const float*)d_in[4];
  const float* Wh = (const float*)d_in[5];
  const float* b_lstm = (const float*)d_in[6];
  const float* w1 = (const float*)d_in[7];  const float* b1 = (const float*)d_in[8];
  const float* w2 = (const float*)d_in[9];  const float* b2 = (const float*)d_in[10];
  const float* w3 = (const float*)d_in[11]; const float* b3 = (const float*)d_in[12];
  const float* w4 = (const float*)d_in[13]; const float* b4 = (const float*)d_in[14];
  const float* w5 = (const float*)d_in[15]; const float* b5 = (const float*)d_in[16];
  const float* w6 = (const float*)d_in[17]; const float* b6 = (const float*)d_in[18];
  const float* w7 = (const float*)d_in[19]; const float* b7 = (const float*)d_in[20];
  const float* w8 = (const float*)d_in[21]; const float* b8 = (const float*)d_in[22];
  const float* w9 = (const float*)d_in[23]; const float* b9 = (const float*)d_in[24];
  const float* alpha = (const float*)d_in[25];
  const float* beta = (const float*)d_in[26];
  const float* mu0 = (const float*)d_in[27];
  __bf16* ws = (__bf16*)d_ws;

  auto S = [](const float* ptr, int row0, int len) {
    PSeg s; s.p = ptr; s.row0 = row0; s.len = len; return s;
  };
  PSeg Zs; Zs.p = nullptr; Zs.row0 = 0; Zs.len = 0;
  auto L = [&](PSeg a, PSeg b, PSeg c, int K, int N, unsigned off) {
    int total = (K / 32) * (N / 16) * 64;
    pack_w<<<(total + 255) / 256, 256, 0, stream>>>(a, b, c, K, N, ws + off);
  };
  L(S(Wx, 0, 64), S(Wx, 320, 128), S(Wh, 0, 256), 448, 1024, PW_GS);  // [z|yp|h]
  L(S(Wx, 64, 256), Zs, Zs, 256, 1024, PW_GHI);
  L(S(w1, 0, 256), Zs, Zs, 256, 128, PW_W1);
  L(S(w2, 0, 128), Zs, Zs, 128, 128, PW_W2);
  L(S(w3, 0, 128), Zs, Zs, 128, 128, PW_W3);
  L(S(w4, 256, 512), Zs, Zs, 512, 64, PW_W4S);  // [c|y|yp]
  L(S(w4, 0, 256), Zs, Zs, 256, 64, PW_W4H);
  L(S(w5, 0, 64), Zs, Zs, 64, 64, PW_W5);
  L(S(w6, 0, 64), Zs, Zs, 64, 64, PW_W6);
  L(S(w7, 256, 384), Zs, Zs, 384, 64, PW_W7S);  // [c|yp]
  L(S(w7, 0, 256), Zs, Zs, 256, 64, PW_W7H);
  L(S(w8, 0, 64), Zs, Zs, 64, 64, PW_W8);
  L(S(w9, 0, 64), Zs, Zs, 64, 64, PW_W9);

  Params p;
  p.h_i = h_i; p.input_t = input_t; p.eps_inf = eps_inf; p.eps_prior = eps_prior;
  p.b_lstm = b_lstm; p.b1 = b1; p.b2 = b2; p.b3 = b3; p.b4 = b4; p.b5 = b5;
  p.b6 = b6; p.b7 = b7; p.b8 = b8; p.b9 = b9;
  p.alpha = alpha; p.beta = beta; p.mu0 = mu0;
  p.wpack = ws;
  p.out = (float*)d_out;

  decoder_main<<<256, 1024, 0, stream>>>(p);
}

// Round 4
// 2421.780 us; speedup vs baseline: 1.9614x; 1.1096x over previous
//
#include <hip/hip_runtime.h>

// ---------------------------------------------------------------------------
// Fused decoder: B=8192 x 40 steps, one WG of 1024 threads (16 waves) per 32
// rows, grid=256 (1 WG/CU, 4 waves/SIMD). 16x16x32 bf16 MFMA.
// R4: explicit batch-preload of weight fragments into registers per phase
// (MLP 4-12 instead of ~1), rotating depth-2 prefetch across the gates GEMM
// kept warm across steps. eps loads issued at phase start.
// ---------------------------------------------------------------------------

#define BDIM  8192
#define HDIM  256
#define FDIM  128
#define ZDIM  64
#define TDIM  43
#define STEPS 40

typedef __attribute__((ext_vector_type(8))) __bf16 bf16x8;
typedef __attribute__((ext_vector_type(4))) float  f32x4;

// LDS activation buffer (cols are bf16 elements)
#define ACT_STRIDE 3248   // bytes/row; 812 dw == 12 (mod 32), +16B stagger per 8 rows
#define C_Z   0           // z          (64)
#define C_Y0  64          // y parity 0 (128)
#define C_Y1  192         // y parity 1 (128)
#define C_H0  320         // h parity 0 (256)
#define C_H1  576         // h parity 1 (256)
#define C_C   832         // c_new      (256)   (holds h_i during startup folds)
#define C_T0  1088        // y1         (128)
#define C_T1  1216        // y2         (128)
#define C_HZ  1344        // hz  (inf)  (64)
#define C_HZP 1408        // hzp (prior)(64)
#define C_B4  1472        // h_i@w4+b4 fold, bf16 (64)
#define C_B7  1536        // h_i@w7+b7 fold, bf16 (64)  -> 1600 cols

// packed-weight offsets in __bf16 elements
#define PW_GS  0u         // gates [z|yp|h] K=448 N=1024 (KT=14)
#define PW_GHI 458752u    // gates h_i part K=256 N=1024 (KT=8)
#define PW_W1  720896u    // K=256 N=128 (KT=8)
#define PW_W2  753664u    // K=128 N=128 (KT=4)
#define PW_W3  770048u    // K=128 N=128 (KT=4)
#define PW_W4S 786432u    // w4 rows 256:768 [c|y|yp] K=512 N=64 (KT=16)
#define PW_W4H 819200u    // w4 rows 0:256 K=256 N=64 (KT=8)
#define PW_W5  835584u    // K=64 N=64 (KT=2)
#define PW_W6  839680u
#define PW_W7S 843776u    // w7 rows 256:640 [c|yp] K=384 N=64 (KT=12)
#define PW_W7H 868352u    // w7 rows 0:256 K=256 N=64 (KT=8)
#define PW_W8  884736u
#define PW_W9  888832u

__device__ __forceinline__ int act_off(int row, int col) {
  return row * ACT_STRIDE + ((row >> 3) << 4) + (col << 1);
}
__device__ __forceinline__ f32x4 mfma16(bf16x8 a, bf16x8 b, f32x4 c) {
  return __builtin_amdgcn_mfma_f32_16x16x32_bf16(a, b, c, 0, 0, 0);
}
__device__ __forceinline__ float sigm(float x) { return 1.f / (1.f + __expf(-x)); }
__device__ __forceinline__ float tanh_f(float x) {
  float t = __expf(-2.f * fabsf(x));
  float r = (1.f - t) / (1.f + t);
  return x < 0.f ? -r : r;
}
// A-fragment read: lane l holds A[mt*16 + (l&15)][k = (l>>4)*8 + j]
__device__ __forceinline__ bf16x8 aread(const unsigned char* actb, int mt, int col,
                                        int lane) {
  return *(const bf16x8*)(actb + act_off(mt * 16 + (lane & 15), col + ((lane >> 4) << 3)));
}
// C-fragment store with bias+relu: row = mt*16 + (lane>>4)*4 + r
__device__ __forceinline__ void st16(unsigned char* actb, int col, int mt, int rsub,
                                     f32x4 v, float bv) {
#pragma unroll
  for (int r = 0; r < 4; ++r)
    *(__bf16*)(actb + act_off(mt * 16 + rsub + r, col)) = (__bf16)fmaxf(v[r] + bv, 0.f);
}
__device__ __forceinline__ unsigned int pk2(float a, float b) {
  union { __bf16 h; unsigned short u; } x, y;
  x.h = (__bf16)a; y.h = (__bf16)b;
  return (unsigned int)x.u | ((unsigned int)y.u << 16);
}
__device__ __forceinline__ float upkf(unsigned int u, int hi) {
  union { unsigned int i; float f; } c;
  c.i = hi ? (u & 0xffff0000u) : (u << 16);
  return c.f;
}

// ---------------------------------------------------------------------------
// Pack (up to 3 K-stacked row segments) into 16-wide B-fragments:
// frag f=(nt*KT+kt)*64+lane holds W[kt*32+(lane>>4)*8+j][nt*16+(lane&15)].
// ---------------------------------------------------------------------------
struct PSeg { const float* p; int row0; int len; };

__global__ __launch_bounds__(256) void pack_w(PSeg s0, PSeg s1, PSeg s2,
                                              int K, int N, __bf16* __restrict__ dst) {
  int f = blockIdx.x * 256 + threadIdx.x;
  int KT = K >> 5;
  int total = KT * (N >> 4) * 64;
  if (f >= total) return;
  int lane = f & 63;
  int tile = f >> 6;
  int kt = tile % KT;
  int nt = tile / KT;
  int k0 = kt * 32 + ((lane >> 4) << 3);
  int n = (nt << 4) + (lane & 15);
  bf16x8 v;
#pragma unroll
  for (int j = 0; j < 8; ++j) {
    int k = k0 + j;
    const float* src;
    int r;
    if (k < s0.len) { src = s0.p; r = s0.row0 + k; }
    else if (k < s0.len + s1.len) { src = s1.p; r = s1.row0 + (k - s0.len); }
    else { src = s2.p; r = s2.row0 + (k - s0.len - s1.len); }
    v[j] = (__bf16)src[(size_t)r * N + n];
  }
  *(bf16x8*)(dst + (size_t)f * 8) = v;
}

struct Params {
  const float *h_i, *input_t, *eps_inf, *eps_prior;
  const float *b_lstm, *b1, *b2, *b3, *b4, *b5, *b6, *b7, *b8, *b9;
  const float *alpha, *beta, *mu0;
  const __bf16* wpack;
  float* out;
};

// load one kt-slice (4 gate fragments) of the gates weights into wb[t]
#define LDA(t, ktv)                                                         \
  do {                                                                      \
    _Pragma("unroll") for (int g = 0; g < 4; ++g) wb[t][g] =                \
        wgs[((size_t)(g * 16 + w) * 14 + (ktv)) * 64 + lane];               \
  } while (0)

__global__ __launch_bounds__(1024, 4) void decoder_main(Params p) {
  __shared__ __align__(16) unsigned char act[32 * ACT_STRIDE];  // 103936 B
  __shared__ float fbuf[2048];                                  // 8192 B
  __shared__ float inten[STEPS * 32];                           // 5120 B

  const int tid = threadIdx.x;
  const int w = tid >> 6;
  const int lane = tid & 63;
  const int ln16 = lane & 15;
  const int rsub = (lane >> 4) << 2;
  const int r0 = blockIdx.x * 32;

  for (int i = tid; i < (32 * ACT_STRIDE) / 4; i += 1024) ((unsigned int*)act)[i] = 0u;
  __syncthreads();
  // stage h_i bf16 into C_C (consumed by the startup folds only)
  for (int i = tid; i < 32 * 256; i += 1024) {
    int row = i >> 8, col = i & 255;
    *(__bf16*)(act + act_off(row, C_C + col)) =
        (__bf16)p.h_i[(size_t)(r0 + row) * HDIM + col];
  }
  {
    float ab = p.alpha[0] * p.beta[0], mu = p.mu0[0];
    for (int t = tid; t < 32 * STEPS; t += 1024) {
      int row = t & 31, j = t >> 5;
      const float* tp = p.input_t + (size_t)(r0 + row) * TDIM;
      float tc = tp[j + 3];
      float s = 0.f;
      for (int idx = 0; idx < j + 3; ++idx) s += __expf(tp[idx] - tc);
      inten[j * 32 + row] = mu + ab * s;
    }
  }
  __syncthreads();

  const __bf16* W = p.wpack;
  const bf16x8* wgs = (const bf16x8*)(W + PW_GS);
  const bf16x8* wghi = (const bf16x8*)(W + PW_GHI);
  const bf16x8* w1p = (const bf16x8*)(W + PW_W1);
  const bf16x8* w2p = (const bf16x8*)(W + PW_W2);
  const bf16x8* w3p = (const bf16x8*)(W + PW_W3);
  const bf16x8* w4s = (const bf16x8*)(W + PW_W4S);
  const bf16x8* w4h = (const bf16x8*)(W + PW_W4H);
  const bf16x8* w5p = (const bf16x8*)(W + PW_W5);
  const bf16x8* w6p = (const bf16x8*)(W + PW_W6);
  const bf16x8* w7s = (const bf16x8*)(W + PW_W7S);
  const bf16x8* w7h = (const bf16x8*)(W + PW_W7H);
  const bf16x8* w8p = (const bf16x8*)(W + PW_W8);
  const bf16x8* w9p = (const bf16x8*)(W + PW_W9);

  // ---- startup folds ----
  uint2 gbp[4][2];  // h_i@Wx_hi + b_lstm, packed bf16 per gate/mtile
  {
    f32x4 g[4][2] = {};
#pragma unroll
    for (int kt = 0; kt < 8; ++kt) {
      bf16x8 a0 = aread(act, 0, C_C + kt * 32, lane);
      bf16x8 a1 = aread(act, 1, C_C + kt * 32, lane);
#pragma unroll
      for (int gg = 0; gg < 4; ++gg) {
        bf16x8 b = wghi[((size_t)(gg * 16 + w) * 8 + kt) * 64 + lane];
        g[gg][0] = mfma16(a0, b, g[gg][0]);
        g[gg][1] = mfma16(a1, b, g[gg][1]);
      }
    }
#pragma unroll
    for (int gg = 0; gg < 4; ++gg) {
      float bv = p.b_lstm[gg * 256 + w * 16 + ln16];
#pragma unroll
      for (int mt = 0; mt < 2; ++mt) {
        gbp[gg][mt].x = pk2(g[gg][mt][0] + bv, g[gg][mt][1] + bv);
        gbp[gg][mt].y = pk2(g[gg][mt][2] + bv, g[gg][mt][3] + bv);
      }
    }
  }
  {  // h_i@w4h+b4 -> C_B4 (waves 0-7); h_i@w7h+b7 -> C_B7 (waves 8-15)
    int n = w & 3, mt = (w >> 2) & 1;
    const bf16x8* wp = (w < 8) ? w4h : w7h;
    const float* bb = (w < 8) ? p.b4 : p.b7;
    int cb = (w < 8) ? C_B4 : C_B7;
    f32x4 v = {};
#pragma unroll
    for (int kt = 0; kt < 8; ++kt)
      v = mfma16(aread(act, mt, C_C + kt * 32, lane),
                 wp[(size_t)(n * 8 + kt) * 64 + lane], v);
    float bv = bb[n * 16 + ln16];
#pragma unroll
    for (int r = 0; r < 4; ++r)
      *(__bf16*)(act + act_off(mt * 16 + rsub + r, cb + n * 16 + ln16)) =
          (__bf16)(v[r] + bv);
  }
  f32x4 c_st[2] = {};
  __syncthreads();

  float* outy = p.out;
  float* outm = p.out + (size_t)BDIM * STEPS * FDIM;
  float* outl = outm + (size_t)BDIM * STEPS * ZDIM;
  float* outz = outl + (size_t)BDIM * STEPS * ZDIM;
  float* outzp = outz + (size_t)BDIM * STEPS * ZDIM;

  // rotating gates-weight prefetch, kept warm across steps
  bf16x8 wb[2][4];
  LDA(0, 0);
  LDA(1, 1);

  for (int j = 0; j < STEPS; ++j) {
    const int yW = (j & 1) ? C_Y1 : C_Y0, yR = (j & 1) ? C_Y0 : C_Y1;
    const int hW = (j & 1) ? C_H1 : C_H0, hR = (j & 1) ? C_H0 : C_H1;

    // ---- A: gates = [z|yp|h]@Wgs + gb; wave w owns cols w*16 of all 4 gates
    {
      f32x4 acc[4][2] = {};
#pragma unroll
      for (int kt = 0; kt < 14; ++kt) {
        int col = (kt < 2) ? (C_Z + kt * 32)
                           : (kt < 6) ? (yR + (kt - 2) * 32) : (hR + (kt - 6) * 32);
        bf16x8 a0 = aread(act, 0, col, lane);
        bf16x8 a1 = aread(act, 1, col, lane);
#pragma unroll
        for (int g = 0; g < 4; ++g) {
          acc[g][0] = mfma16(a0, wb[kt & 1][g], acc[g][0]);
          acc[g][1] = mfma16(a1, wb[kt & 1][g], acc[g][1]);
        }
        if (kt + 2 < 14) LDA(kt & 1, kt + 2);
      }
#pragma unroll
      for (int mt = 0; mt < 2; ++mt) {
#pragma unroll
        for (int r = 0; r < 4; ++r) {
          int row = mt * 16 + rsub + r;
          unsigned int ui = (r < 2) ? gbp[0][mt].x : gbp[0][mt].y;
          unsigned int uf = (r < 2) ? gbp[1][mt].x : gbp[1][mt].y;
          unsigned int ug = (r < 2) ? gbp[2][mt].x : gbp[2][mt].y;
          unsigned int uo = (r < 2) ? gbp[3][mt].x : gbp[3][mt].y;
          float ig = sigm(acc[0][mt][r] + upkf(ui, r & 1));
          float fg = sigm(acc[1][mt][r] + upkf(uf, r & 1));
          float gg = tanh_f(acc[2][mt][r] + upkf(ug, r & 1));
          float og = sigm(acc[3][mt][r] + upkf(uo, r & 1));
          float cn = fg * c_st[mt][r] + ig * gg;
          float hn = og * tanh_f(cn);
          c_st[mt][r] = inten[j * 32 + row] * cn;
          *(__bf16*)(act + act_off(row, C_C + w * 16 + ln16)) = (__bf16)cn;
          *(__bf16*)(act + act_off(row, hW + w * 16 + ln16)) = (__bf16)hn;
        }
      }
    }
    __syncthreads();

    // ---- B: w0-7 y1 = relu(h@w1+b1); w8-15 full-K prior -> hzp
    if (w < 8) {
      bf16x8 wf[8];
#pragma unroll
      for (int kt = 0; kt < 8; ++kt) wf[kt] = w1p[(size_t)(w * 8 + kt) * 64 + lane];
      f32x4 a0 = {}, a1 = {};
#pragma unroll
      for (int kt = 0; kt < 8; ++kt) {
        a0 = mfma16(aread(act, 0, hW + kt * 32, lane), wf[kt], a0);
        a1 = mfma16(aread(act, 1, hW + kt * 32, lane), wf[kt], a1);
      }
      float bv = p.b1[w * 16 + ln16];
      st16(act, C_T0 + w * 16 + ln16, 0, rsub, a0, bv);
      st16(act, C_T0 + w * 16 + ln16, 1, rsub, a1, bv);
    } else {
      int n = w & 3, mt = (w >> 2) & 1;
      bf16x8 wf[12];
#pragma unroll
      for (int kt = 0; kt < 12; ++kt) wf[kt] = w7s[(size_t)(n * 12 + kt) * 64 + lane];
      f32x4 v = {};
#pragma unroll
      for (int kt = 0; kt < 12; ++kt) {
        int col = (kt < 8) ? (C_C + kt * 32) : (yR + (kt - 8) * 32);
        v = mfma16(aread(act, mt, col, lane), wf[kt], v);
      }
#pragma unroll
      for (int r = 0; r < 4; ++r) {
        int row = mt * 16 + rsub + r;
        float s = v[r] + (float)*(const __bf16*)(act + act_off(row, C_B7 + n * 16 + ln16));
        *(__bf16*)(act + act_off(row, C_HZP + n * 16 + ln16)) = (__bf16)fmaxf(s, 0.f);
      }
    }
    __syncthreads();

    // ---- C: w0-7 y2; w8-15 mean_p/lv_p + sample zp (prior done)
    if (w < 8) {
      bf16x8 wf[4];
#pragma unroll
      for (int kt = 0; kt < 4; ++kt) wf[kt] = w2p[(size_t)(w * 4 + kt) * 64 + lane];
      f32x4 a0 = {}, a1 = {};
#pragma unroll
      for (int kt = 0; kt < 4; ++kt) {
        a0 = mfma16(aread(act, 0, C_T0 + kt * 32, lane), wf[kt], a0);
        a1 = mfma16(aread(act, 1, C_T0 + kt * 32, lane), wf[kt], a1);
      }
      float bv = p.b2[w * 16 + ln16];
      st16(act, C_T1 + w * 16 + ln16, 0, rsub, a0, bv);
      st16(act, C_T1 + w * 16 + ln16, 1, rsub, a1, bv);
    } else {
      int n = w & 3, mt = (w >> 2) & 1;
      float ep[4];
#pragma unroll
      for (int r = 0; r < 4; ++r)
        ep[r] = __builtin_nontemporal_load(
            p.eps_prior + ((size_t)j * BDIM + r0 + mt * 16 + rsub + r) * ZDIM +
            n * 16 + ln16);
      bf16x8 wm[2], wl[2];
#pragma unroll
      for (int kt = 0; kt < 2; ++kt) {
        wm[kt] = w8p[(size_t)(n * 2 + kt) * 64 + lane];
        wl[kt] = w9p[(size_t)(n * 2 + kt) * 64 + lane];
      }
      f32x4 vm = {}, vl = {};
#pragma unroll
      for (int kt = 0; kt < 2; ++kt) {
        bf16x8 a = aread(act, mt, C_HZP + kt * 32, lane);
        vm = mfma16(a, wm[kt], vm);
        vl = mfma16(a, wl[kt], vl);
      }
      float bm = p.b8[n * 16 + ln16], bl = p.b9[n * 16 + ln16];
#pragma unroll
      for (int r = 0; r < 4; ++r) {
        int row = mt * 16 + rsub + r, col = n * 16 + ln16;
        float mp = fmaxf(vm[r] + bm, 0.f), lp = fmaxf(vl[r] + bl, 0.f);
        float zp = mp + ep[r] * __expf(0.5f * lp);
        __builtin_nontemporal_store(
            zp, outzp + ((size_t)(r0 + row) * STEPS + j) * ZDIM + col);
      }
    }
    __syncthreads();

    // ---- D: w0-7 y3 -> yW + outy; w8-15 hz partial over [c|yp]
    if (w < 8) {
      bf16x8 wf[4];
#pragma unroll
      for (int kt = 0; kt < 4; ++kt) wf[kt] = w3p[(size_t)(w * 4 + kt) * 64 + lane];
      f32x4 a0 = {}, a1 = {};
#pragma unroll
      for (int kt = 0; kt < 4; ++kt) {
        a0 = mfma16(aread(act, 0, C_T1 + kt * 32, lane), wf[kt], a0);
        a1 = mfma16(aread(act, 1, C_T1 + kt * 32, lane), wf[kt], a1);
      }
      float bv = p.b3[w * 16 + ln16];
#pragma unroll
      for (int mt = 0; mt < 2; ++mt) {
        f32x4 vv = mt ? a1 : a0;
#pragma unroll
        for (int r = 0; r < 4; ++r) {
          int row = mt * 16 + rsub + r;
          float yv = fmaxf(vv[r] + bv, 0.f);
          *(__bf16*)(act + act_off(row, yW + w * 16 + ln16)) = (__bf16)yv;
          __builtin_nontemporal_store(
              yv, outy + ((size_t)(r0 + row) * STEPS + j) * FDIM + w * 16 + ln16);
        }
      }
    } else {
      int a = w - 8, n = a & 3, mt = a >> 2;
      bf16x8 wf[12];
#pragma unroll
      for (int kk = 0; kk < 12; ++kk) {
        int kt = (kk < 8) ? kk : (kk + 4);  // kt 0..7 (c) and 12..15 (yp)
        wf[kk] = w4s[(size_t)(n * 16 + kt) * 64 + lane];
      }
      f32x4 v = {};
#pragma unroll
      for (int kk = 0; kk < 12; ++kk) {
        int col = (kk < 8) ? (C_C + kk * 32) : (yR + (kk - 8) * 32);
        v = mfma16(aread(act, mt, col, lane), wf[kk], v);
      }
#pragma unroll
      for (int r = 0; r < 4; ++r)
        fbuf[(mt * 16 + rsub + r) * 64 + n * 16 + ln16] = v[r];
    }
    __syncthreads();

    // ---- E: w0-7 hz y-part + combine partial + fold -> C_HZ
    if (w < 8) {
      int n = w & 3, mt = w >> 2;
      bf16x8 wf[4];
#pragma unroll
      for (int kt = 8; kt < 12; ++kt) wf[kt - 8] = w4s[(size_t)(n * 16 + kt) * 64 + lane];
      f32x4 v = {};
#pragma unroll
      for (int kt = 8; kt < 12; ++kt)
        v = mfma16(aread(act, mt, yW + (kt - 8) * 32, lane), wf[kt - 8], v);
#pragma unroll
      for (int r = 0; r < 4; ++r) {
        int row = mt * 16 + rsub + r, cc = n * 16 + ln16;
        float s = v[r] + fbuf[row * 64 + cc] +
                  (float)*(const __bf16*)(act + act_off(row, C_B4 + cc));
        *(__bf16*)(act + act_off(row, C_HZ + cc)) = (__bf16)fmaxf(s, 0.f);
      }
    }
    __syncthreads();

    // ---- F: w0-7 mean_j/lv_j + sample z -> outputs + C_Z
    if (w < 8) {
      int n = w & 3, mt = w >> 2;
      float ei[4];
#pragma unroll
      for (int r = 0; r < 4; ++r)
        ei[r] = __builtin_nontemporal_load(
            p.eps_inf + ((size_t)j * BDIM + r0 + mt * 16 + rsub + r) * ZDIM +
            n * 16 + ln16);
      bf16x8 wm[2], wl[2];
#pragma unroll
      for (int kt = 0; kt < 2; ++kt) {
        wm[kt] = w5p[(size_t)(n * 2 + kt) * 64 + lane];
        wl[kt] = w6p[(size_t)(n * 2 + kt) * 64 + lane];
      }
      f32x4 vm = {}, vl = {};
#pragma unroll
      for (int kt = 0; kt < 2; ++kt) {
        bf16x8 a = aread(act, mt, C_HZ + kt * 32, lane);
        vm = mfma16(a, wm[kt], vm);
        vl = mfma16(a, wl[kt], vl);
      }
      float bm = p.b5[n * 16 + ln16], bl = p.b6[n * 16 + ln16];
#pragma unroll
      for (int r = 0; r < 4; ++r) {
        int row = mt * 16 + rsub + r, col = n * 16 + ln16;
        float m = fmaxf(vm[r] + bm, 0.f), l = fmaxf(vl[r] + bl, 0.f);
        float zn = m + ei[r] * __expf(0.5f * l);
        size_t ob = ((size_t)(r0 + row) * STEPS + j) * ZDIM + col;
        __builtin_nontemporal_store(m, outm + ob);
        __builtin_nontemporal_store(l, outl + ob);
        __builtin_nontemporal_store(zn, outz + ob);
        *(__bf16*)(act + act_off(row, C_Z + col)) = (__bf16)zn;
      }
    }
    // refill gates prefetch for next step (survives the barrier in regs)
    if (j + 1 < STEPS) {
      LDA(0, 0);
      LDA(1, 1);
    }
    __syncthreads();
  }
}

extern "C" void kernel_launch(void* const* d_in, const int* in_sizes, int n_in,
                              void* d_out, int out_size, void* d_ws, size_t ws_size,
                              hipStream_t stream) {
  const float* h_i = (const float*)d_in[0];
  const float* input_t = (const float*)d_in[1];
  const float* eps_inf = (const float*)d_in[2];
  const float* eps_prior = (const float*)d_in[3];
  const float* Wx = (const float*)d_in[4];
  const float* Wh = (const float*)d_in[5];
  const float* b_lstm = (const float*)d_in[6];
  const float* w1 = (const float*)d_in[7];  const float* b1 = (const float*)d_in[8];
  const float* w2 = (const float*)d_in[9];  const float* b2 = (const float*)d_in[10];
  const float* w3 = (const float*)d_in[11]; const float* b3 = (const float*)d_in[12];
  const float* w4 = (const float*)d_in[13]; const float* b4 = (const float*)d_in[14];
  const float* w5 = (const float*)d_in[15]; const float* b5 = (const float*)d_in[16];
  const float* w6 = (const float*)d_in[17]; const float* b6 = (const float*)d_in[18];
  const float* w7 = (const float*)d_in[19]; const float* b7 = (const float*)d_in[20];
  const float* w8 = (const float*)d_in[21]; const float* b8 = (const float*)d_in[22];
  const float* w9 = (const float*)d_in[23]; const float* b9 = (const float*)d_in[24];
  const float* alpha = (const float*)d_in[25];
  const float* beta = (const float*)d_in[26];
  const float* mu0 = (const float*)d_in[27];
  __bf16* ws = (__bf16*)d_ws;

  auto S = [](const float* ptr, int row0, int len) {
    PSeg s; s.p = ptr; s.row0 = row0; s.len = len; return s;
  };
  PSeg Zs; Zs.p = nullptr; Zs.row0 = 0; Zs.len = 0;
  auto L = [&](PSeg a, PSeg b, PSeg c, int K, int N, unsigned off) {
    int total = (K / 32) * (N / 16) * 64;
    pack_w<<<(total + 255) / 256, 256, 0, stream>>>(a, b, c, K, N, ws + off);
  };
  L(S(Wx, 0, 64), S(Wx, 320, 128), S(Wh, 0, 256), 448, 1024, PW_GS);  // [z|yp|h]
  L(S(Wx, 64, 256), Zs, Zs, 256, 1024, PW_GHI);
  L(S(w1, 0, 256), Zs, Zs, 256, 128, PW_W1);
  L(S(w2, 0, 128), Zs, Zs, 128, 128, PW_W2);
  L(S(w3, 0, 128), Zs, Zs, 128, 128, PW_W3);
  L(S(w4, 256, 512), Zs, Zs, 512, 64, PW_W4S);  // [c|y|yp]
  L(S(w4, 0, 256), Zs, Zs, 256, 64, PW_W4H);
  L(S(w5, 0, 64), Zs, Zs, 64, 64, PW_W5);
  L(S(w6, 0, 64), Zs, Zs, 64, 64, PW_W6);
  L(S(w7, 256, 384), Zs, Zs, 384, 64, PW_W7S);  // [c|yp]
  L(S(w7, 0, 256), Zs, Zs, 256, 64, PW_W7H);
  L(S(w8, 0, 64), Zs, Zs, 64, 64, PW_W8);
  L(S(w9, 0, 64), Zs, Zs, 64, 64, PW_W9);

  Params p;
  p.h_i = h_i; p.input_t = input_t; p.eps_inf = eps_inf; p.eps_prior = eps_prior;
  p.b_lstm = b_lstm; p.b1 = b1; p.b2 = b2; p.b3 = b3; p.b4 = b4; p.b5 = b5;
  p.b6 = b6; p.b7 = b7; p.b8 = b8; p.b9 = b9;
  p.alpha = alpha; p.beta = beta; p.mu0 = mu0;
  p.wpack = ws;
  p.out = (float*)d_out;

  decoder_main<<<256, 1024, 0, stream>>>(p);
}

// Round 5
// 2402.724 us; speedup vs baseline: 1.9770x; 1.0079x over previous
//
#include <hip/hip_runtime.h>

// ---------------------------------------------------------------------------
// Fused decoder: B=8192 x 40 steps, one WG of 1024 threads (16 waves) per 32
// rows, grid=256 (1 WG/CU, 4 waves/SIMD). 16x16x32 bf16 MFMA.
// R5: amdgpu_waves_per_eu(4,4) unlocks 128 VGPR; raw barriers (lgkmcnt-only
// drain) keep weight loads in flight across phases; depth-3 rotating gates
// prefetch refilled across the step boundary (issued at phase E).
// ---------------------------------------------------------------------------

#define BDIM  8192
#define HDIM  256
#define FDIM  128
#define ZDIM  64
#define TDIM  43
#define STEPS 40

typedef __attribute__((ext_vector_type(8))) __bf16 bf16x8;
typedef __attribute__((ext_vector_type(4))) float  f32x4;

// LDS activation buffer (cols are bf16 elements)
#define ACT_STRIDE 3248   // bytes/row; 812 dw == 12 (mod 32), +16B stagger per 8 rows
#define C_Z   0           // z          (64)
#define C_Y0  64          // y parity 0 (128)
#define C_Y1  192         // y parity 1 (128)
#define C_H0  320         // h parity 0 (256)
#define C_H1  576         // h parity 1 (256)
#define C_C   832         // c_new      (256)   (holds h_i during startup folds)
#define C_T0  1088        // y1         (128)
#define C_T1  1216        // y2         (128)
#define C_HZ  1344        // hz  (inf)  (64)
#define C_HZP 1408        // hzp (prior)(64)
#define C_B4  1472        // h_i@w4+b4 fold, bf16 (64)
#define C_B7  1536        // h_i@w7+b7 fold, bf16 (64)  -> 1600 cols

// packed-weight offsets in __bf16 elements
#define PW_GS  0u         // gates [z|yp|h] K=448 N=1024 (KT=14)
#define PW_GHI 458752u    // gates h_i part K=256 N=1024 (KT=8)
#define PW_W1  720896u    // K=256 N=128 (KT=8)
#define PW_W2  753664u    // K=128 N=128 (KT=4)
#define PW_W3  770048u    // K=128 N=128 (KT=4)
#define PW_W4S 786432u    // w4 rows 256:768 [c|y|yp] K=512 N=64 (KT=16)
#define PW_W4H 819200u    // w4 rows 0:256 K=256 N=64 (KT=8)
#define PW_W5  835584u    // K=64 N=64 (KT=2)
#define PW_W6  839680u
#define PW_W7S 843776u    // w7 rows 256:640 [c|yp] K=384 N=64 (KT=12)
#define PW_W7H 868352u    // w7 rows 0:256 K=256 N=64 (KT=8)
#define PW_W8  884736u
#define PW_W9  888832u

__device__ __forceinline__ int act_off(int row, int col) {
  return row * ACT_STRIDE + ((row >> 3) << 4) + (col << 1);
}
__device__ __forceinline__ f32x4 mfma16(bf16x8 a, bf16x8 b, f32x4 c) {
  return __builtin_amdgcn_mfma_f32_16x16x32_bf16(a, b, c, 0, 0, 0);
}
__device__ __forceinline__ float sigm(float x) { return 1.f / (1.f + __expf(-x)); }
__device__ __forceinline__ float tanh_f(float x) {
  float t = __expf(-2.f * fabsf(x));
  float r = (1.f - t) / (1.f + t);
  return x < 0.f ? -r : r;
}
// LDS-drain-only barrier: weight/eps loads + output stores (vmcnt) stay in
// flight across phases; LDS producer->consumer ordering is preserved.
__device__ __forceinline__ void wg_barrier() {
  asm volatile("s_waitcnt lgkmcnt(0)" ::: "memory");
  __builtin_amdgcn_s_barrier();
  __builtin_amdgcn_sched_barrier(0);
}
// A-fragment read: lane l holds A[mt*16 + (l&15)][k = (l>>4)*8 + j]
__device__ __forceinline__ bf16x8 aread(const unsigned char* actb, int mt, int col,
                                        int lane) {
  return *(const bf16x8*)(actb + act_off(mt * 16 + (lane & 15), col + ((lane >> 4) << 3)));
}
// C-fragment store with bias+relu: row = mt*16 + (lane>>4)*4 + r
__device__ __forceinline__ void st16(unsigned char* actb, int col, int mt, int rsub,
                                     f32x4 v, float bv) {
#pragma unroll
  for (int r = 0; r < 4; ++r)
    *(__bf16*)(actb + act_off(mt * 16 + rsub + r, col)) = (__bf16)fmaxf(v[r] + bv, 0.f);
}
__device__ __forceinline__ unsigned int pk2(float a, float b) {
  union { __bf16 h; unsigned short u; } x, y;
  x.h = (__bf16)a; y.h = (__bf16)b;
  return (unsigned int)x.u | ((unsigned int)y.u << 16);
}
__device__ __forceinline__ float upkf(unsigned int u, int hi) {
  union { unsigned int i; float f; } c;
  c.i = hi ? (u & 0xffff0000u) : (u << 16);
  return c.f;
}

// ---------------------------------------------------------------------------
// Pack (up to 3 K-stacked row segments) into 16-wide B-fragments:
// frag f=(nt*KT+kt)*64+lane holds W[kt*32+(lane>>4)*8+j][nt*16+(lane&15)].
// ---------------------------------------------------------------------------
struct PSeg { const float* p; int row0; int len; };

__global__ __launch_bounds__(256) void pack_w(PSeg s0, PSeg s1, PSeg s2,
                                              int K, int N, __bf16* __restrict__ dst) {
  int f = blockIdx.x * 256 + threadIdx.x;
  int KT = K >> 5;
  int total = KT * (N >> 4) * 64;
  if (f >= total) return;
  int lane = f & 63;
  int tile = f >> 6;
  int kt = tile % KT;
  int nt = tile / KT;
  int k0 = kt * 32 + ((lane >> 4) << 3);
  int n = (nt << 4) + (lane & 15);
  bf16x8 v;
#pragma unroll
  for (int j = 0; j < 8; ++j) {
    int k = k0 + j;
    const float* src;
    int r;
    if (k < s0.len) { src = s0.p; r = s0.row0 + k; }
    else if (k < s0.len + s1.len) { src = s1.p; r = s1.row0 + (k - s0.len); }
    else { src = s2.p; r = s2.row0 + (k - s0.len - s1.len); }
    v[j] = (__bf16)src[(size_t)r * N + n];
  }
  *(bf16x8*)(dst + (size_t)f * 8) = v;
}

struct Params {
  const float *h_i, *input_t, *eps_inf, *eps_prior;
  const float *b_lstm, *b1, *b2, *b3, *b4, *b5, *b6, *b7, *b8, *b9;
  const float *alpha, *beta, *mu0;
  const __bf16* wpack;
  float* out;
};

// load one kt-slice (4 gate fragments) of the gates weights into wb[t]
#define LDA(t, ktv)                                                         \
  do {                                                                      \
    _Pragma("unroll") for (int g = 0; g < 4; ++g) wb[t][g] =                \
        wgs[((size_t)(g * 16 + w) * 14 + (ktv)) * 64 + lane];               \
  } while (0)

__attribute__((amdgpu_waves_per_eu(4, 4)))
__global__ __launch_bounds__(1024) void decoder_main(Params p) {
  __shared__ __align__(16) unsigned char act[32 * ACT_STRIDE];  // 103936 B
  __shared__ float fbuf[2048];                                  // 8192 B
  __shared__ float inten[STEPS * 32];                           // 5120 B

  const int tid = threadIdx.x;
  const int w = tid >> 6;
  const int lane = tid & 63;
  const int ln16 = lane & 15;
  const int rsub = (lane >> 4) << 2;
  const int r0 = blockIdx.x * 32;

  for (int i = tid; i < (32 * ACT_STRIDE) / 4; i += 1024) ((unsigned int*)act)[i] = 0u;
  __syncthreads();
  // stage h_i bf16 into C_C (consumed by the startup folds only)
  for (int i = tid; i < 32 * 256; i += 1024) {
    int row = i >> 8, col = i & 255;
    *(__bf16*)(act + act_off(row, C_C + col)) =
        (__bf16)p.h_i[(size_t)(r0 + row) * HDIM + col];
  }
  {
    float ab = p.alpha[0] * p.beta[0], mu = p.mu0[0];
    for (int t = tid; t < 32 * STEPS; t += 1024) {
      int row = t & 31, j = t >> 5;
      const float* tp = p.input_t + (size_t)(r0 + row) * TDIM;
      float tc = tp[j + 3];
      float s = 0.f;
      for (int idx = 0; idx < j + 3; ++idx) s += __expf(tp[idx] - tc);
      inten[j * 32 + row] = mu + ab * s;
    }
  }
  __syncthreads();

  const __bf16* W = p.wpack;
  const bf16x8* wgs = (const bf16x8*)(W + PW_GS);
  const bf16x8* wghi = (const bf16x8*)(W + PW_GHI);
  const bf16x8* w1p = (const bf16x8*)(W + PW_W1);
  const bf16x8* w2p = (const bf16x8*)(W + PW_W2);
  const bf16x8* w3p = (const bf16x8*)(W + PW_W3);
  const bf16x8* w4s = (const bf16x8*)(W + PW_W4S);
  const bf16x8* w4h = (const bf16x8*)(W + PW_W4H);
  const bf16x8* w5p = (const bf16x8*)(W + PW_W5);
  const bf16x8* w6p = (const bf16x8*)(W + PW_W6);
  const bf16x8* w7s = (const bf16x8*)(W + PW_W7S);
  const bf16x8* w7h = (const bf16x8*)(W + PW_W7H);
  const bf16x8* w8p = (const bf16x8*)(W + PW_W8);
  const bf16x8* w9p = (const bf16x8*)(W + PW_W9);

  // ---- startup folds ----
  uint2 gbp[4][2];  // h_i@Wx_hi + b_lstm, packed bf16 per gate/mtile
  {
    f32x4 g[4][2] = {};
#pragma unroll
    for (int kt = 0; kt < 8; ++kt) {
      bf16x8 a0 = aread(act, 0, C_C + kt * 32, lane);
      bf16x8 a1 = aread(act, 1, C_C + kt * 32, lane);
#pragma unroll
      for (int gg = 0; gg < 4; ++gg) {
        bf16x8 b = wghi[((size_t)(gg * 16 + w) * 8 + kt) * 64 + lane];
        g[gg][0] = mfma16(a0, b, g[gg][0]);
        g[gg][1] = mfma16(a1, b, g[gg][1]);
      }
    }
#pragma unroll
    for (int gg = 0; gg < 4; ++gg) {
      float bv = p.b_lstm[gg * 256 + w * 16 + ln16];
#pragma unroll
      for (int mt = 0; mt < 2; ++mt) {
        gbp[gg][mt].x = pk2(g[gg][mt][0] + bv, g[gg][mt][1] + bv);
        gbp[gg][mt].y = pk2(g[gg][mt][2] + bv, g[gg][mt][3] + bv);
      }
    }
  }
  {  // h_i@w4h+b4 -> C_B4 (waves 0-7); h_i@w7h+b7 -> C_B7 (waves 8-15)
    int n = w & 3, mt = (w >> 2) & 1;
    const bf16x8* wp = (w < 8) ? w4h : w7h;
    const float* bb = (w < 8) ? p.b4 : p.b7;
    int cb = (w < 8) ? C_B4 : C_B7;
    f32x4 v = {};
#pragma unroll
    for (int kt = 0; kt < 8; ++kt)
      v = mfma16(aread(act, mt, C_C + kt * 32, lane),
                 wp[(size_t)(n * 8 + kt) * 64 + lane], v);
    float bv = bb[n * 16 + ln16];
#pragma unroll
    for (int r = 0; r < 4; ++r)
      *(__bf16*)(act + act_off(mt * 16 + rsub + r, cb + n * 16 + ln16)) =
          (__bf16)(v[r] + bv);
  }
  f32x4 c_st[2] = {};
  __syncthreads();

  float* outy = p.out;
  float* outm = p.out + (size_t)BDIM * STEPS * FDIM;
  float* outl = outm + (size_t)BDIM * STEPS * ZDIM;
  float* outz = outl + (size_t)BDIM * STEPS * ZDIM;
  float* outzp = outz + (size_t)BDIM * STEPS * ZDIM;

  // rotating depth-3 gates-weight prefetch, kept warm across steps
  bf16x8 wb[3][4];
  LDA(0, 0);
  LDA(1, 1);
  LDA(2, 2);

  for (int j = 0; j < STEPS; ++j) {
    const int yW = (j & 1) ? C_Y1 : C_Y0, yR = (j & 1) ? C_Y0 : C_Y1;
    const int hW = (j & 1) ? C_H1 : C_H0, hR = (j & 1) ? C_H0 : C_H1;

    // ---- A: gates = [z|yp|h]@Wgs + gb; wave w owns cols w*16 of all 4 gates
    {
      f32x4 acc[4][2] = {};
#pragma unroll
      for (int kt = 0; kt < 14; ++kt) {
        int col = (kt < 2) ? (C_Z + kt * 32)
                           : (kt < 6) ? (yR + (kt - 2) * 32) : (hR + (kt - 6) * 32);
        bf16x8 a0 = aread(act, 0, col, lane);
        bf16x8 a1 = aread(act, 1, col, lane);
        const int s = kt % 3;
#pragma unroll
        for (int g = 0; g < 4; ++g) {
          acc[g][0] = mfma16(a0, wb[s][g], acc[g][0]);
          acc[g][1] = mfma16(a1, wb[s][g], acc[g][1]);
        }
        if (kt + 3 < 14) LDA(s, kt + 3);
      }
#pragma unroll
      for (int mt = 0; mt < 2; ++mt) {
#pragma unroll
        for (int r = 0; r < 4; ++r) {
          int row = mt * 16 + rsub + r;
          unsigned int ui = (r < 2) ? gbp[0][mt].x : gbp[0][mt].y;
          unsigned int uf = (r < 2) ? gbp[1][mt].x : gbp[1][mt].y;
          unsigned int ug = (r < 2) ? gbp[2][mt].x : gbp[2][mt].y;
          unsigned int uo = (r < 2) ? gbp[3][mt].x : gbp[3][mt].y;
          float ig = sigm(acc[0][mt][r] + upkf(ui, r & 1));
          float fg = sigm(acc[1][mt][r] + upkf(uf, r & 1));
          float gg = tanh_f(acc[2][mt][r] + upkf(ug, r & 1));
          float og = sigm(acc[3][mt][r] + upkf(uo, r & 1));
          float cn = fg * c_st[mt][r] + ig * gg;
          float hn = og * tanh_f(cn);
          c_st[mt][r] = inten[j * 32 + row] * cn;
          *(__bf16*)(act + act_off(row, C_C + w * 16 + ln16)) = (__bf16)cn;
          *(__bf16*)(act + act_off(row, hW + w * 16 + ln16)) = (__bf16)hn;
        }
      }
    }
    wg_barrier();

    // ---- B: w0-7 y1 = relu(h@w1+b1); w8-15 full-K prior -> hzp
    if (w < 8) {
      bf16x8 wf[8];
#pragma unroll
      for (int kt = 0; kt < 8; ++kt) wf[kt] = w1p[(size_t)(w * 8 + kt) * 64 + lane];
      f32x4 a0 = {}, a1 = {};
#pragma unroll
      for (int kt = 0; kt < 8; ++kt) {
        a0 = mfma16(aread(act, 0, hW + kt * 32, lane), wf[kt], a0);
        a1 = mfma16(aread(act, 1, hW + kt * 32, lane), wf[kt], a1);
      }
      float bv = p.b1[w * 16 + ln16];
      st16(act, C_T0 + w * 16 + ln16, 0, rsub, a0, bv);
      st16(act, C_T0 + w * 16 + ln16, 1, rsub, a1, bv);
    } else {
      int n = w & 3, mt = (w >> 2) & 1;
      bf16x8 wf[12];
#pragma unroll
      for (int kt = 0; kt < 12; ++kt) wf[kt] = w7s[(size_t)(n * 12 + kt) * 64 + lane];
      f32x4 v = {};
#pragma unroll
      for (int kt = 0; kt < 12; ++kt) {
        int col = (kt < 8) ? (C_C + kt * 32) : (yR + (kt - 8) * 32);
        v = mfma16(aread(act, mt, col, lane), wf[kt], v);
      }
#pragma unroll
      for (int r = 0; r < 4; ++r) {
        int row = mt * 16 + rsub + r;
        float s = v[r] + (float)*(const __bf16*)(act + act_off(row, C_B7 + n * 16 + ln16));
        *(__bf16*)(act + act_off(row, C_HZP + n * 16 + ln16)) = (__bf16)fmaxf(s, 0.f);
      }
    }
    wg_barrier();

    // ---- C: w0-7 y2; w8-15 mean_p/lv_p + sample zp (prior done)
    if (w < 8) {
      bf16x8 wf[4];
#pragma unroll
      for (int kt = 0; kt < 4; ++kt) wf[kt] = w2p[(size_t)(w * 4 + kt) * 64 + lane];
      f32x4 a0 = {}, a1 = {};
#pragma unroll
      for (int kt = 0; kt < 4; ++kt) {
        a0 = mfma16(aread(act, 0, C_T0 + kt * 32, lane), wf[kt], a0);
        a1 = mfma16(aread(act, 1, C_T0 + kt * 32, lane), wf[kt], a1);
      }
      float bv = p.b2[w * 16 + ln16];
      st16(act, C_T1 + w * 16 + ln16, 0, rsub, a0, bv);
      st16(act, C_T1 + w * 16 + ln16, 1, rsub, a1, bv);
    } else {
      int n = w & 3, mt = (w >> 2) & 1;
      float ep[4];
#pragma unroll
      for (int r = 0; r < 4; ++r)
        ep[r] = __builtin_nontemporal_load(
            p.eps_prior + ((size_t)j * BDIM + r0 + mt * 16 + rsub + r) * ZDIM +
            n * 16 + ln16);
      bf16x8 wm[2], wl[2];
#pragma unroll
      for (int kt = 0; kt < 2; ++kt) {
        wm[kt] = w8p[(size_t)(n * 2 + kt) * 64 + lane];
        wl[kt] = w9p[(size_t)(n * 2 + kt) * 64 + lane];
      }
      f32x4 vm = {}, vl = {};
#pragma unroll
      for (int kt = 0; kt < 2; ++kt) {
        bf16x8 a = aread(act, mt, C_HZP + kt * 32, lane);
        vm = mfma16(a, wm[kt], vm);
        vl = mfma16(a, wl[kt], vl);
      }
      float bm = p.b8[n * 16 + ln16], bl = p.b9[n * 16 + ln16];
#pragma unroll
      for (int r = 0; r < 4; ++r) {
        int row = mt * 16 + rsub + r, col = n * 16 + ln16;
        float mp = fmaxf(vm[r] + bm, 0.f), lp = fmaxf(vl[r] + bl, 0.f);
        float zp = mp + ep[r] * __expf(0.5f * lp);
        __builtin_nontemporal_store(
            zp, outzp + ((size_t)(r0 + row) * STEPS + j) * ZDIM + col);
      }
    }
    wg_barrier();

    // ---- D: w0-7 y3 -> yW + outy; w8-15 hz partial over [c|yp]
    if (w < 8) {
      bf16x8 wf[4];
#pragma unroll
      for (int kt = 0; kt < 4; ++kt) wf[kt] = w3p[(size_t)(w * 4 + kt) * 64 + lane];
      f32x4 a0 = {}, a1 = {};
#pragma unroll
      for (int kt = 0; kt < 4; ++kt) {
        a0 = mfma16(aread(act, 0, C_T1 + kt * 32, lane), wf[kt], a0);
        a1 = mfma16(aread(act, 1, C_T1 + kt * 32, lane), wf[kt], a1);
      }
      float bv = p.b3[w * 16 + ln16];
#pragma unroll
      for (int mt = 0; mt < 2; ++mt) {
        f32x4 vv = mt ? a1 : a0;
#pragma unroll
        for (int r = 0; r < 4; ++r) {
          int row = mt * 16 + rsub + r;
          float yv = fmaxf(vv[r] + bv, 0.f);
          *(__bf16*)(act + act_off(row, yW + w * 16 + ln16)) = (__bf16)yv;
          __builtin_nontemporal_store(
              yv, outy + ((size_t)(r0 + row) * STEPS + j) * FDIM + w * 16 + ln16);
        }
      }
    } else {
      int a = w - 8, n = a & 3, mt = a >> 2;
      bf16x8 wf[12];
#pragma unroll
      for (int kk = 0; kk < 12; ++kk) {
        int kt = (kk < 8) ? kk : (kk + 4);  // kt 0..7 (c) and 12..15 (yp)
        wf[kk] = w4s[(size_t)(n * 16 + kt) * 64 + lane];
      }
      f32x4 v = {};
#pragma unroll
      for (int kk = 0; kk < 12; ++kk) {
        int col = (kk < 8) ? (C_C + kk * 32) : (yR + (kk - 8) * 32);
        v = mfma16(aread(act, mt, col, lane), wf[kk], v);
      }
#pragma unroll
      for (int r = 0; r < 4; ++r)
        fbuf[(mt * 16 + rsub + r) * 64 + n * 16 + ln16] = v[r];
    }
    wg_barrier();

    // ---- E: refill next-step gates prefetch (in flight across barriers),
    //      then w0-7 hz y-part + combine partial + fold -> C_HZ
    LDA(0, 0);
    LDA(1, 1);
    LDA(2, 2);
    if (w < 8) {
      int n = w & 3, mt = w >> 2;
      bf16x8 wf[4];
#pragma unroll
      for (int kt = 8; kt < 12; ++kt) wf[kt - 8] = w4s[(size_t)(n * 16 + kt) * 64 + lane];
      f32x4 v = {};
#pragma unroll
      for (int kt = 8; kt < 12; ++kt)
        v = mfma16(aread(act, mt, yW + (kt - 8) * 32, lane), wf[kt - 8], v);
#pragma unroll
      for (int r = 0; r < 4; ++r) {
        int row = mt * 16 + rsub + r, cc = n * 16 + ln16;
        float s = v[r] + fbuf[row * 64 + cc] +
                  (float)*(const __bf16*)(act + act_off(row, C_B4 + cc));
        *(__bf16*)(act + act_off(row, C_HZ + cc)) = (__bf16)fmaxf(s, 0.f);
      }
    }
    wg_barrier();

    // ---- F: w0-7 mean_j/lv_j + sample z -> outputs + C_Z
    if (w < 8) {
      int n = w & 3, mt = w >> 2;
      float ei[4];
#pragma unroll
      for (int r = 0; r < 4; ++r)
        ei[r] = __builtin_nontemporal_load(
            p.eps_inf + ((size_t)j * BDIM + r0 + mt * 16 + rsub + r) * ZDIM +
            n * 16 + ln16);
      bf16x8 wm[2], wl[2];
#pragma unroll
      for (int kt = 0; kt < 2; ++kt) {
        wm[kt] = w5p[(size_t)(n * 2 + kt) * 64 + lane];
        wl[kt] = w6p[(size_t)(n * 2 + kt) * 64 + lane];
      }
      f32x4 vm = {}, vl = {};
#pragma unroll
      for (int kt = 0; kt < 2; ++kt) {
        bf16x8 a = aread(act, mt, C_HZ + kt * 32, lane);
        vm = mfma16(a, wm[kt], vm);
        vl = mfma16(a, wl[kt], vl);
      }
      float bm = p.b5[n * 16 + ln16], bl = p.b6[n * 16 + ln16];
#pragma unroll
      for (int r = 0; r < 4; ++r) {
        int row = mt * 16 + rsub + r, col = n * 16 + ln16;
        float m = fmaxf(vm[r] + bm, 0.f), l = fmaxf(vl[r] + bl, 0.f);
        float zn = m + ei[r] * __expf(0.5f * l);
        size_t ob = ((size_t)(r0 + row) * STEPS + j) * ZDIM + col;
        __builtin_nontemporal_store(m, outm + ob);
        __builtin_nontemporal_store(l, outl + ob);
        __builtin_nontemporal_store(zn, outz + ob);
        *(__bf16*)(act + act_off(row, C_Z + col)) = (__bf16)zn;
      }
    }
    wg_barrier();
  }
}

extern "C" void kernel_launch(void* const* d_in, const int* in_sizes, int n_in,
                              void* d_out, int out_size, void* d_ws, size_t ws_size,
                              hipStream_t stream) {
  const float* h_i = (const float*)d_in[0];
  const float* input_t = (const float*)d_in[1];
  const float* eps_inf = (const float*)d_in[2];
  const float* eps_prior = (const float*)d_in[3];
  const float* Wx = (const float*)d_in[4];
  const float* Wh = (const float*)d_in[5];
  const float* b_lstm = (const float*)d_in[6];
  const float* w1 = (const float*)d_in[7];  const float* b1 = (const float*)d_in[8];
  const float* w2 = (const float*)d_in[9];  const float* b2 = (const float*)d_in[10];
  const float* w3 = (const float*)d_in[11]; const float* b3 = (const float*)d_in[12];
  const float* w4 = (const float*)d_in[13]; const float* b4 = (const float*)d_in[14];
  const float* w5 = (const float*)d_in[15]; const float* b5 = (const float*)d_in[16];
  const float* w6 = (const float*)d_in[17]; const float* b6 = (const float*)d_in[18];
  const float* w7 = (const float*)d_in[19]; const float* b7 = (const float*)d_in[20];
  const float* w8 = (const float*)d_in[21]; const float* b8 = (const float*)d_in[22];
  const float* w9 = (const float*)d_in[23]; const float* b9 = (const float*)d_in[24];
  const float* alpha = (const float*)d_in[25];
  const float* beta = (const float*)d_in[26];
  const float* mu0 = (const float*)d_in[27];
  __bf16* ws = (__bf16*)d_ws;

  auto S = [](const float* ptr, int row0, int len) {
    PSeg s; s.p = ptr; s.row0 = row0; s.len = len; return s;
  };
  PSeg Zs; Zs.p = nullptr; Zs.row0 = 0; Zs.len = 0;
  auto L = [&](PSeg a, PSeg b, PSeg c, int K, int N, unsigned off) {
    int total = (K / 32) * (N / 16) * 64;
    pack_w<<<(total + 255) / 256, 256, 0, stream>>>(a, b, c, K, N, ws + off);
  };
  L(S(Wx, 0, 64), S(Wx, 320, 128), S(Wh, 0, 256), 448, 1024, PW_GS);  // [z|yp|h]
  L(S(Wx, 64, 256), Zs, Zs, 256, 1024, PW_GHI);
  L(S(w1, 0, 256), Zs, Zs, 256, 128, PW_W1);
  L(S(w2, 0, 128), Zs, Zs, 128, 128, PW_W2);
  L(S(w3, 0, 128), Zs, Zs, 128, 128, PW_W3);
  L(S(w4, 256, 512), Zs, Zs, 512, 64, PW_W4S);  // [c|y|yp]
  L(S(w4, 0, 256), Zs, Zs, 256, 64, PW_W4H);
  L(S(w5, 0, 64), Zs, Zs, 64, 64, PW_W5);
  L(S(w6, 0, 64), Zs, Zs, 64, 64, PW_W6);
  L(S(w7, 256, 384), Zs, Zs, 384, 64, PW_W7S);  // [c|yp]
  L(S(w7, 0, 256), Zs, Zs, 256, 64, PW_W7H);
  L(S(w8, 0, 64), Zs, Zs, 64, 64, PW_W8);
  L(S(w9, 0, 64), Zs, Zs, 64, 64, PW_W9);

  Params p;
  p.h_i = h_i; p.input_t = input_t; p.eps_inf = eps_inf; p.eps_prior = eps_prior;
  p.b_lstm = b_lstm; p.b1 = b1; p.b2 = b2; p.b3 = b3; p.b4 = b4; p.b5 = b5;
  p.b6 = b6; p.b7 = b7; p.b8 = b8; p.b9 = b9;
  p.alpha = alpha; p.beta = beta; p.mu0 = mu0;
  p.wpack = ws;
  p.out = (float*)d_out;

  decoder_main<<<256, 1024, 0, stream>>>(p);
}